// Round 5
// baseline (190.004 us; speedup 1.0000x reference)
//
#include <hip/hip_runtime.h>
#include <hip/hip_bf16.h>
#include <cmath>

typedef _Float16 half_t;
typedef half_t half4 __attribute__((ext_vector_type(4)));
typedef half_t half8 __attribute__((ext_vector_type(8)));
typedef float f32x4 __attribute__((ext_vector_type(4)));

#define N_HEADS 16
#define HD      64
#define T_SEQ   2048
#define B_SZ    2
#define C_DIM   1024
#define M_ROWS  (B_SZ * T_SEQ)   /* 4096 */
#define N_QKV   (3 * C_DIM)      /* 3072 */
#define QSCALE  0.18033688f      /* 0.125 * log2(e), folded into Q at rope */

__device__ inline void load_lds16(const half_t* g, half_t* l) {
  __builtin_amdgcn_global_load_lds(
      (const __attribute__((address_space(1))) void*)g,
      (__attribute__((address_space(3))) void*)l, 16, 0, 0);
}

// ---- fused prep: x->f16 (0..4095), w_attn^T (..4863), w_proj^T (..5119),
// ---- rope cos/sin table (5120..5375): tbl[t][j] = {cos,sin}(t*10000^(-j/32))
__global__ __launch_bounds__(256) void k_prep(const float* __restrict__ x,
                                              half_t* __restrict__ xb,
                                              const float* __restrict__ wa,
                                              half_t* __restrict__ wT,
                                              const float* __restrict__ wp,
                                              half_t* __restrict__ wpT,
                                              float2* __restrict__ tbl) {
  __shared__ float tile[64][65];
  int bid = blockIdx.x, tid = threadIdx.x;
  if (bid < 4096) {
    int i = (bid * 256 + tid) * 4;
    float4 v = *(const float4*)(x + i);
    half_t o[4] = {(half_t)v.x, (half_t)v.y, (half_t)v.z, (half_t)v.w};
    *(ulong1*)(xb + i) = *(ulong1*)o;
    return;
  }
  if (bid >= 5120) {                       // rope table: 65536 entries
    int idx = (bid - 5120) * 256 + tid;
    int t = idx >> 5, j = idx & 31;
    float inv = exp2f(-(float)j * (13.287712379549449f / 32.0f));
    float s, c;
    sincosf((float)t * inv, &s, &c);
    tbl[idx] = make_float2(c, s);
    return;
  }
  const float* in; half_t* out; int K, N, id;
  if (bid < 4864) { id = bid - 4096; in = wa; out = wT;  K = 1024; N = 3072; }
  else            { id = bid - 4864; in = wp; out = wpT; K = 1024; N = 1024; }
  int n0 = (id % (N / 64)) * 64, k0 = (id / (N / 64)) * 64;
  int tx = tid & 63, ty = tid >> 6;
  #pragma unroll
  for (int i = 0; i < 64; i += 4)
    tile[ty + i][tx] = in[(size_t)(k0 + ty + i) * N + n0 + tx];
  __syncthreads();
  #pragma unroll
  for (int i = 0; i < 64; i += 4) {
    int r = ty + i;
    out[(size_t)(n0 + r) * K + k0 + tx] = (half_t)tile[tx][r];
  }
}

// ------------- GEMM: C = A(f16,[M][K]) * Bt(f16,[N][K])^T + bias, OT out ----
// 128xTN tile, BK=64, global_load_lds width-16 into XOR-swizzled LDS.
template <typename OT, int TN>
__global__ __launch_bounds__(256) void k_gemm(const half_t* __restrict__ A,
                                              const half_t* __restrict__ Bt,
                                              const float* __restrict__ bias,
                                              OT* __restrict__ C,
                                              int M, int N, int K) {
  constexpr int NI = TN / 32;          // n-fragments per wave
  __shared__ half_t As[128 * 64];
  __shared__ half_t Bs[TN * 64];
  int tid = threadIdx.x;
  int wave = tid >> 6, lane = tid & 63;
  int lane15 = lane & 15, quad = lane >> 4;
  int wm = (wave >> 1) * 64, wn = (wave & 1) * (TN / 2);
  int bm0 = blockIdx.y * 128, bn0 = blockIdx.x * TN;
  f32x4 acc[4][NI] = {};

  for (int kb = 0; kb < K; kb += 64) {
    const half_t* Ag = A + (size_t)bm0 * K + kb;
    const half_t* Bg = Bt + (size_t)bn0 * K + kb;
    __syncthreads();
    #pragma unroll
    for (int p = 0; p < 4; p++) {
      int fc = wave * 4 * 64 + p * 64 + lane;
      int r = fc >> 3, c = (fc & 7) ^ (r & 7);
      load_lds16(Ag + (size_t)r * K + c * 8, As + (wave * 4 + p) * 512);
    }
    #pragma unroll
    for (int p = 0; p < NI; p++) {
      int fc = wave * NI * 64 + p * 64 + lane;
      int r = fc >> 3, c = (fc & 7) ^ (r & 7);
      load_lds16(Bg + (size_t)r * K + c * 8, Bs + (wave * NI + p) * 512);
    }
    __syncthreads();
    #pragma unroll
    for (int ks = 0; ks < 2; ks++) {
      half8 af[4], bf[NI];
      #pragma unroll
      for (int i = 0; i < 4; i++) {
        int Ra = wm + i * 16 + lane15;
        af[i] = *(const half8*)(As + Ra * 64 + ((ks * 4 + quad) ^ (Ra & 7)) * 8);
      }
      #pragma unroll
      for (int i = 0; i < NI; i++) {
        int Rb = wn + i * 16 + lane15;
        bf[i] = *(const half8*)(Bs + Rb * 64 + ((ks * 4 + quad) ^ (Rb & 7)) * 8);
      }
      #pragma unroll
      for (int mi = 0; mi < 4; mi++)
        #pragma unroll
        for (int ni = 0; ni < NI; ni++)
          acc[mi][ni] = __builtin_amdgcn_mfma_f32_16x16x32_f16(af[mi], bf[ni], acc[mi][ni], 0, 0, 0);
    }
  }
  #pragma unroll
  for (int mi = 0; mi < 4; mi++)
    #pragma unroll
    for (int ni = 0; ni < NI; ni++) {
      int n = bn0 + wn + ni * 16 + lane15;
      float bv = bias[n];
      int mrow = bm0 + wm + mi * 16 + quad * 4;
      #pragma unroll
      for (int r = 0; r < 4; r++)
        C[(size_t)(mrow + r) * N + n] = (OT)(acc[mi][ni][r] + bv);
    }
}

// ------------- fused QKV GEMM + bias + RoPE + reorg (C^T fragments) -------------
// R4 lesson: the straight acc layout (thread owns 4 rows x 1 col) forced 32
// scalar 2B stores + 32 scattered 8B tbl loads per thread. v2 SWAPS the MFMA
// operands (acc[ni][mi] = mfma(bf,af,.)), so each thread owns 4 CONSECUTIVE n
// (=d) values for one row m=lane15:
//   Q/K: rope pair (d,d+32) = acc[p][mi]/acc[p+2][mi]; two half4 stores per
//        (mi,p), tbl read = two contiguous float4, bias = one float4 per ni.
//   V:   LDS transpose writes become half4 (stride 132 keeps 8B alignment),
//        then blocked store Vt[bh][t/64][d][t%64] (contiguous 8KB per kv tile).
__global__ __launch_bounds__(256) void k_gemm_qkv(const half_t* __restrict__ A,
                                                  const half_t* __restrict__ Bt,
                                                  const float* __restrict__ bias,
                                                  const float2* __restrict__ tbl,
                                                  half_t* __restrict__ Qo,
                                                  half_t* __restrict__ Ko,
                                                  half_t* __restrict__ Vo) {
  __shared__ half_t smem[16896];           // As 8192 | Bs 8192 ; V: vt[128][132]
  half_t* As = smem;
  half_t* Bs = smem + 8192;
  int tid = threadIdx.x;
  int wave = tid >> 6, lane = tid & 63;
  int lane15 = lane & 15, quad = lane >> 4;
  int wm = (wave >> 1) * 64, wn = (wave & 1) * 64;
  int bm0 = blockIdx.y * 128, bn0 = blockIdx.x * 128;
  f32x4 acc[4][4] = {};                    // acc[ni][mi]: col=lane15 (m), row=quad*4+r (n)

  for (int kb = 0; kb < C_DIM; kb += 64) {
    const half_t* Ag = A + (size_t)bm0 * C_DIM + kb;
    const half_t* Bg = Bt + (size_t)bn0 * C_DIM + kb;
    __syncthreads();
    #pragma unroll
    for (int p = 0; p < 4; p++) {
      int fc = wave * 4 * 64 + p * 64 + lane;
      int r = fc >> 3, c = (fc & 7) ^ (r & 7);
      load_lds16(Ag + (size_t)r * C_DIM + c * 8, As + (wave * 4 + p) * 512);
    }
    #pragma unroll
    for (int p = 0; p < 4; p++) {
      int fc = wave * 4 * 64 + p * 64 + lane;
      int r = fc >> 3, c = (fc & 7) ^ (r & 7);
      load_lds16(Bg + (size_t)r * C_DIM + c * 8, Bs + (wave * 4 + p) * 512);
    }
    __syncthreads();
    #pragma unroll
    for (int ks = 0; ks < 2; ks++) {
      half8 af[4], bf[4];
      #pragma unroll
      for (int i = 0; i < 4; i++) {
        int Ra = wm + i * 16 + lane15;
        af[i] = *(const half8*)(As + Ra * 64 + ((ks * 4 + quad) ^ (Ra & 7)) * 8);
      }
      #pragma unroll
      for (int i = 0; i < 4; i++) {
        int Rb = wn + i * 16 + lane15;
        bf[i] = *(const half8*)(Bs + Rb * 64 + ((ks * 4 + quad) ^ (Rb & 7)) * 8);
      }
      #pragma unroll
      for (int ni = 0; ni < 4; ni++)
        #pragma unroll
        for (int mi = 0; mi < 4; mi++)
          acc[ni][mi] = __builtin_amdgcn_mfma_f32_16x16x32_f16(bf[ni], af[mi], acc[ni][mi], 0, 0, 0);
    }
  }
  // bias (b_attn) BEFORE rope, matching reference; float4 along n
  #pragma unroll
  for (int ni = 0; ni < 4; ni++) {
    float4 bv4 = *(const float4*)(bias + bn0 + wn + ni * 16 + quad * 4);
    #pragma unroll
    for (int mi = 0; mi < 4; mi++)
      #pragma unroll
      for (int r = 0; r < 4; r++) acc[ni][mi][r] += ((const float*)&bv4)[r];
  }

  int third = bn0 >> 10;                   // 0=Q, 1=K, 2=V (block-uniform)
  if (third < 2) {
    half_t* Ob = (third == 0) ? Qo : Ko;
    int h = ((bn0 & 1023) + wn) >> 6;      // head for this wave's columns
    #pragma unroll
    for (int mi = 0; mi < 4; mi++) {
      int m = bm0 + wm + mi * 16 + lane15;
      int bq = m >> 11, tq = m & 2047;
      half_t* outp = Ob + ((size_t)(bq * 16 + h) * T_SEQ + tq) * HD;
      #pragma unroll
      for (int p = 0; p < 2; p++) {        // d0..d0+3 paired with d0+32..+35
        int d0 = p * 16 + quad * 4;
        const float4* tb4 = (const float4*)(tbl + (size_t)tq * 32 + d0);
        float4 t0 = tb4[0], t1 = tb4[1];   // c0 s0 c1 s1 | c2 s2 c3 s3
        float cs_c[4] = {t0.x, t0.z, t1.x, t1.z};
        float cs_s[4] = {t0.y, t0.w, t1.y, t1.w};
        half4 o1, o2;
        #pragma unroll
        for (int r = 0; r < 4; r++) {
          float a1 = acc[p][mi][r], a2 = acc[p + 2][mi][r];
          float f1 = a1 * cs_c[r] - a2 * cs_s[r];
          float f2 = a1 * cs_s[r] + a2 * cs_c[r];
          if (third == 0) { f1 *= QSCALE; f2 *= QSCALE; }
          o1[r] = (half_t)f1;
          o2[r] = (half_t)f2;
        }
        *(half4*)(outp + d0)      = o1;
        *(half4*)(outp + d0 + 32) = o2;
      }
    }
  } else {
    // V: transpose through LDS (half4 writes), store blocked [bh][t/64][d][t%64]
    __syncthreads();                       // all waves done reading As/Bs
    #pragma unroll
    for (int mi = 0; mi < 4; mi++) {
      int tl = wm + mi * 16 + lane15;
      #pragma unroll
      for (int ni = 0; ni < 4; ni++) {
        int nl = wn + ni * 16 + quad * 4;
        half4 o;
        #pragma unroll
        for (int r = 0; r < 4; r++) o[r] = (half_t)acc[ni][mi][r];
        *(half4*)(&smem[tl * 132 + nl]) = o;
      }
    }
    __syncthreads();
    int hV = (bn0 - 2048) >> 6;
    int bq = bm0 >> 11, tq0 = bm0 & 2047;
    int c8 = (tid & 7) * 8;                // 8 lanes cover one 64-t row chunk
    #pragma unroll
    for (int p = 0; p < 8; p++) {
      int gr = p * 32 + (tid >> 3);        // 256 rows: (h2, d, tblk)
      int tb = gr & 1, d = (gr >> 1) & 63, h2 = gr >> 7;
      half8 vv;
      #pragma unroll
      for (int jj = 0; jj < 8; jj++)
        vv[jj] = smem[(tb * 64 + c8 + jj) * 132 + h2 * 64 + d];
      *(half8*)(Vo + ((size_t)((bq * 16 + hV + h2) * 32 + (tq0 >> 6) + tb) * 64 + d) * 64 + c8) = vv;
    }
  }
}

// ------------- causal flash v3: 128-q tiles, kv-split-2, 16 waves -------------
// 16 waves: waves 0-7 = group 0 (even kv tiles), 8-15 = group 1 (odd).
// Rounds per 128-q tile = qt+1; block does tiles x and 15-x -> 17 rounds for
// EVERY block. Grid (8,32) = 256 blocks = 1/CU, 16 waves/CU steady, no tail.
// V is kv-tile-blocked [bh][tile][d][64]: stage reads are contiguous 8KB.
template <bool DIAG>
__device__ __forceinline__ void tile_mfma(const half_t* __restrict__ Kt,
                                          const half_t* __restrict__ Vt,
                                          half8 bq0, half8 bq1,
                                          f32x4 (&ot)[4], float& l,
                                          int lane15, int quad, int qloc) {
  f32x4 sacc[4];
  #pragma unroll
  for (int s = 0; s < 4; s++) {
    int R_ = s * 16 + lane15;
    half8 ak0 = *(const half8*)(Kt + R_ * 64 + ((quad) ^ (R_ & 7)) * 8);
    half8 ak1 = *(const half8*)(Kt + R_ * 64 + ((4 + quad) ^ (R_ & 7)) * 8);
    f32x4 z = {};
    z = __builtin_amdgcn_mfma_f32_16x16x32_f16(ak0, bq0, z, 0, 0, 0);
    sacc[s] = __builtin_amdgcn_mfma_f32_16x16x32_f16(ak1, bq1, z, 0, 0, 0);
  }
  #pragma unroll
  for (int s = 0; s < 4; s++) {
    half4 bp;
    #pragma unroll
    for (int r = 0; r < 4; r++) {
      float sv = sacc[s][r];
      if (DIAG && (s * 16 + quad * 4 + r > qloc)) sv = -1.0e30f;
      float p = exp2f(fminf(sv, 14.0f));
      l += p;
      bp[r] = (half_t)p;
    }
    #pragma unroll
    for (int nm = 0; nm < 4; nm++) {
      int Rv = nm * 16 + lane15;
      half4 av = *(const half4*)(Vt + Rv * 64 +
                                 ((2 * s + (quad >> 1)) ^ (Rv & 7)) * 8 +
                                 (quad & 1) * 4);
      ot[nm] = __builtin_amdgcn_mfma_f32_16x16x16f16(av, bp, ot[nm], 0, 0, 0);
    }
  }
}

// Stage kv tiles {2t, 2t+1} of K and V into buffer bb. 1024 threads, each
// issues 1 K + 1 V load_lds16 (16B): waves 0-7 serve group 0's tile (2t),
// waves 8-15 serve group 1's tile (2t+1). 32KB total per stage.
#define STAGE(bb, t_)                                                          \
  {                                                                            \
    int gS = wave >> 3;                                                        \
    int idx = (wave & 7) * 64 + lane;                                          \
    int rr_ = idx >> 3, cc = (idx & 7) ^ (rr_ & 7);                            \
    int j = 2 * (t_) + gS;                                                     \
    load_lds16(Kb + (size_t)(j * 64 + rr_) * HD + cc * 8,                      \
               &KV[bb][0][gS][0] + idx * 8);                                   \
    load_lds16(Vb + (size_t)j * 4096 + rr_ * 64 + cc * 8,                      \
               &KV[bb][1][gS][0] + idx * 8);                                   \
  }

__device__ __forceinline__ void process_tile(
    int qt, const half_t* __restrict__ Qb, const half_t* __restrict__ Kb,
    const half_t* __restrict__ Vb, half_t* __restrict__ y, int b, int h,
    half_t (&KV)[2][2][2][4096],
    int wave, int lane, int g, int wq, int lane15, int quad) {
  int q0 = qt * 128;
  int qrow = q0 + wq * 16 + lane15;        // this wave's q column (S^T B-op n)
  half8 bq0 = *(const half8*)(Qb + (size_t)qrow * HD + quad * 8);
  half8 bq1 = *(const half8*)(Qb + (size_t)qrow * HD + 32 + quad * 8);
  f32x4 ot[4] = {};                        // O^T: d = nm*16+quad*4+r, q = lane15
  float l = 0.f;
  int R = qt + 1;                          // rounds: group g does kv tile 2r+g
  // hot loop: rounds 0..R-2, both groups unmasked
  for (int r = 0; r < R - 1; r++) {
    __syncthreads();                       // stage(r) DMA drained & visible
    STAGE((r + 1) & 1, r + 1);             // prefetch overlaps compute
    tile_mfma<false>(&KV[r & 1][0][g][0], &KV[r & 1][1][g][0], bq0, bq1, ot, l,
                     lane15, quad, 0);
  }
  // last round (r = R-1): group 0 on tile 2qt (diag for wq<4, auto-full for
  // wq>=4 since qloc>=64>srow); group 1 on tile 2qt+1 (skip wq<4, diag wq>=4)
  __syncthreads();
  {
    int buf = (R - 1) & 1;
    const half_t* Kt = &KV[buf][0][g][0];
    const half_t* Vt = &KV[buf][1][g][0];
    if (g == 0)
      tile_mfma<true>(Kt, Vt, bq0, bq1, ot, l, lane15, quad, wq * 16 + lane15);
    else if (wq >= 4)
      tile_mfma<true>(Kt, Vt, bq0, bq1, ot, l, lane15, quad,
                      (wq - 4) * 16 + lane15);
  }
  // per-wave l: sum the 4 quads holding this q-column
  l += __shfl_xor(l, 16);
  l += __shfl_xor(l, 32);
  // cross-group combine via LDS (reuse KV region, 512*17*4B = 34.8KB <= 64KB)
  __syncthreads();                         // all compute reads of K/V done
  float* cb = (float*)&KV[0][0][0][0];
  int ci = (wq * 64 + lane) * 17;          // stride 17 floats: conflict-free
  if (g == 1) {
    #pragma unroll
    for (int nm = 0; nm < 4; nm++)
      #pragma unroll
      for (int r = 0; r < 4; r++) cb[ci + nm * 4 + r] = ot[nm][r];
    cb[ci + 16] = l;
  }
  __syncthreads();
  if (g == 0) {
    #pragma unroll
    for (int nm = 0; nm < 4; nm++)
      #pragma unroll
      for (int r = 0; r < 4; r++) ot[nm][r] += cb[ci + nm * 4 + r];
    l += cb[ci + 16];
    float invl = 1.0f / l;
    int t = q0 + wq * 16 + lane15;
    half_t* yr = y + (size_t)(b * T_SEQ + t) * C_DIM + h * 64;
    #pragma unroll
    for (int nm = 0; nm < 4; nm++) {
      half4 o4;
      #pragma unroll
      for (int r = 0; r < 4; r++) o4[r] = (half_t)(ot[nm][r] * invl);
      *(half4*)(yr + nm * 16 + quad * 4) = o4;   // 8B store
    }
  }
  __syncthreads();                         // combine region free before restage
}

__global__ __launch_bounds__(1024, 4) void k_flash(const half_t* __restrict__ Qg,
                                                   const half_t* __restrict__ Kg,
                                                   const half_t* __restrict__ Vg,
                                                   half_t* __restrict__ y) {
  __shared__ half_t KV[2][2][2][4096];     // [buf][K/V][grp][64*64]
  int bh = blockIdx.y;
  int b = bh >> 4, h = bh & 15;
  int x = blockIdx.x;                      // 0..7: q-tile pair (x, 15-x)
  int tid = threadIdx.x;
  int wave = tid >> 6, lane = tid & 63;
  int g = wave >> 3, wq = wave & 7;        // kv-parity group, q-warp in group
  int lane15 = lane & 15, quad = lane >> 4;
  const half_t* Qb = Qg + (size_t)bh * T_SEQ * HD;
  const half_t* Kb = Kg + (size_t)bh * T_SEQ * HD;
  const half_t* Vb = Vg + (size_t)bh * HD * T_SEQ;

  int qtA = x, qtB = 15 - x;
  STAGE(0, 0);
  process_tile(qtA, Qb, Kb, Vb, y, b, h, KV, wave, lane, g, wq, lane15, quad);
  STAGE(0, 0);                             // one un-overlapped stage per block
  process_tile(qtB, Qb, Kb, Vb, y, b, h, KV, wave, lane, g, wq, lane15, quad);
  #undef STAGE
}

extern "C" void kernel_launch(void* const* d_in, const int* in_sizes, int n_in,
                              void* d_out, int out_size, void* d_ws, size_t ws_size,
                              hipStream_t stream) {
  const float* x      = (const float*)d_in[0];
  const float* w_attn = (const float*)d_in[1];
  const float* b_attn = (const float*)d_in[2];
  const float* w_proj = (const float*)d_in[3];
  const float* b_proj = (const float*)d_in[4];
  float* out = (float*)d_out;

  char* ws = (char*)d_ws;
  const size_t MB = 1u << 20;
  half_t* xb  = (half_t*)(ws);             // 8 MB  x in f16
  half_t* wT  = (half_t*)(ws + 8 * MB);    // 6 MB  w_attn^T f16 [3072][1024]
  half_t* wpT = (half_t*)(ws + 14 * MB);   // 2 MB  w_proj^T f16 [1024][1024]
  half_t* Q   = (half_t*)(ws + 16 * MB);   // 8 MB  [bh][t][d]  (pre-scaled)
  half_t* Kb  = (half_t*)(ws + 24 * MB);   // 8 MB  [bh][t][d]
  half_t* Vt  = (half_t*)(ws + 32 * MB);   // 8 MB  [bh][t/64][d][t%64] blocked
  half_t* y   = (half_t*)(ws + 40 * MB);   // 8 MB  attn out f16
  float2* tbl = (float2*)(ws + 48 * MB);   // 512KB rope table [2048][32]

  k_prep<<<4096 + 768 + 256 + 256, 256, 0, stream>>>(x, xb, w_attn, wT,
                                                     w_proj, wpT, tbl);
  k_gemm_qkv<<<dim3(N_QKV / 128, M_ROWS / 128), 256, 0, stream>>>(
      xb, wT, b_attn, tbl, Q, Kb, Vt);
  k_flash<<<dim3(8, B_SZ * N_HEADS), 1024, 0, stream>>>(Q, Kb, Vt, y);
  k_gemm<float, 64><<<dim3(C_DIM / 64, M_ROWS / 128), 256, 0, stream>>>(
      y, wpT, b_proj, out, M_ROWS, C_DIM, C_DIM);
}

// Round 7
// 184.186 us; speedup vs baseline: 1.0316x; 1.0316x over previous
//
#include <hip/hip_runtime.h>
#include <hip/hip_bf16.h>
#include <cmath>

typedef _Float16 half_t;
typedef half_t half4 __attribute__((ext_vector_type(4)));
typedef half_t half8 __attribute__((ext_vector_type(8)));
typedef float f32x4 __attribute__((ext_vector_type(4)));

#define N_HEADS 16
#define HD      64
#define T_SEQ   2048
#define B_SZ    2
#define C_DIM   1024
#define M_ROWS  (B_SZ * T_SEQ)   /* 4096 */
#define N_QKV   (3 * C_DIM)      /* 3072 */
#define QSCALE  0.18033688f      /* 0.125 * log2(e), folded into Q at rope */

__device__ inline void load_lds16(const half_t* g, half_t* l) {
  __builtin_amdgcn_global_load_lds(
      (const __attribute__((address_space(1))) void*)g,
      (__attribute__((address_space(3))) void*)l, 16, 0, 0);
}

// ---- fused prep: x->f16 (0..4095), w_attn^T (..4863), w_proj^T (..5119),
// ---- rope cos/sin table (5120..5375): tbl[t][j] = {cos,sin}(t*10000^(-j/32))
__global__ __launch_bounds__(256) void k_prep(const float* __restrict__ x,
                                              half_t* __restrict__ xb,
                                              const float* __restrict__ wa,
                                              half_t* __restrict__ wT,
                                              const float* __restrict__ wp,
                                              half_t* __restrict__ wpT,
                                              float2* __restrict__ tbl) {
  __shared__ float tile[64][65];
  int bid = blockIdx.x, tid = threadIdx.x;
  if (bid < 4096) {
    int i = (bid * 256 + tid) * 4;
    float4 v = *(const float4*)(x + i);
    half_t o[4] = {(half_t)v.x, (half_t)v.y, (half_t)v.z, (half_t)v.w};
    *(ulong1*)(xb + i) = *(ulong1*)o;
    return;
  }
  if (bid >= 5120) {                       // rope table: 65536 entries
    int idx = (bid - 5120) * 256 + tid;
    int t = idx >> 5, j = idx & 31;
    float inv = exp2f(-(float)j * (13.287712379549449f / 32.0f));
    float s, c;
    sincosf((float)t * inv, &s, &c);
    tbl[idx] = make_float2(c, s);
    return;
  }
  const float* in; half_t* out; int K, N, id;
  if (bid < 4864) { id = bid - 4096; in = wa; out = wT;  K = 1024; N = 3072; }
  else            { id = bid - 4864; in = wp; out = wpT; K = 1024; N = 1024; }
  int n0 = (id % (N / 64)) * 64, k0 = (id / (N / 64)) * 64;
  int tx = tid & 63, ty = tid >> 6;
  #pragma unroll
  for (int i = 0; i < 64; i += 4)
    tile[ty + i][tx] = in[(size_t)(k0 + ty + i) * N + n0 + tx];
  __syncthreads();
  #pragma unroll
  for (int i = 0; i < 64; i += 4) {
    int r = ty + i;
    out[(size_t)(n0 + r) * K + k0 + tx] = (half_t)tile[tx][r];
  }
}

// ------------- GEMM: C = A(f16,[M][K]) * Bt(f16,[N][K])^T + bias, OT out ----
// 128xTN tile, BK=64. R6: DOUBLE-BUFFERED prefetch (flash-style): one barrier
// per K-iter, DMA for tile kt+1 issued right after it, compute on tile kt.
// The old sync;stage;sync;compute exposed full global->LDS latency x16 iters.
template <typename OT, int TN>
__global__ __launch_bounds__(256) void k_gemm(const half_t* __restrict__ A,
                                              const half_t* __restrict__ Bt,
                                              const float* __restrict__ bias,
                                              OT* __restrict__ C,
                                              int M, int N, int K) {
  constexpr int NI = TN / 32;          // n-fragments per wave
  __shared__ half_t As[2][128 * 64];
  __shared__ half_t Bs[2][TN * 64];
  int tid = threadIdx.x;
  int wave = tid >> 6, lane = tid & 63;
  int lane15 = lane & 15, quad = lane >> 4;
  int wm = (wave >> 1) * 64, wn = (wave & 1) * (TN / 2);
  int bm0 = blockIdx.y * 128, bn0 = blockIdx.x * TN;
  f32x4 acc[4][NI] = {};

#define G_STAGE(bb, kb)                                                        \
  {                                                                            \
    const half_t* Ag = A + (size_t)bm0 * K + (kb);                             \
    const half_t* Bg = Bt + (size_t)bn0 * K + (kb);                            \
    _Pragma("unroll")                                                          \
    for (int p = 0; p < 4; p++) {                                              \
      int fc = wave * 4 * 64 + p * 64 + lane;                                  \
      int r = fc >> 3, c = (fc & 7) ^ (r & 7);                                 \
      load_lds16(Ag + (size_t)r * K + c * 8, &As[bb][0] + (wave * 4 + p) * 512); \
    }                                                                          \
    _Pragma("unroll")                                                          \
    for (int p = 0; p < NI; p++) {                                             \
      int fc = wave * NI * 64 + p * 64 + lane;                                 \
      int r = fc >> 3, c = (fc & 7) ^ (r & 7);                                 \
      load_lds16(Bg + (size_t)r * K + c * 8, &Bs[bb][0] + (wave * NI + p) * 512); \
    }                                                                          \
  }

  G_STAGE(0, 0);
  int NT = K / 64;
  for (int kt = 0; kt < NT; kt++) {
    __syncthreads();                       // buf[kt&1] DMA drained & visible
    if (kt + 1 < NT) G_STAGE((kt + 1) & 1, (kt + 1) * 64);
    const half_t* Asb = &As[kt & 1][0];
    const half_t* Bsb = &Bs[kt & 1][0];
    #pragma unroll
    for (int ks = 0; ks < 2; ks++) {
      half8 af[4], bf[NI];
      #pragma unroll
      for (int i = 0; i < 4; i++) {
        int Ra = wm + i * 16 + lane15;
        af[i] = *(const half8*)(Asb + Ra * 64 + ((ks * 4 + quad) ^ (Ra & 7)) * 8);
      }
      #pragma unroll
      for (int i = 0; i < NI; i++) {
        int Rb = wn + i * 16 + lane15;
        bf[i] = *(const half8*)(Bsb + Rb * 64 + ((ks * 4 + quad) ^ (Rb & 7)) * 8);
      }
      #pragma unroll
      for (int mi = 0; mi < 4; mi++)
        #pragma unroll
        for (int ni = 0; ni < NI; ni++)
          acc[mi][ni] = __builtin_amdgcn_mfma_f32_16x16x32_f16(af[mi], bf[ni], acc[mi][ni], 0, 0, 0);
    }
  }
#undef G_STAGE
  #pragma unroll
  for (int mi = 0; mi < 4; mi++)
    #pragma unroll
    for (int ni = 0; ni < NI; ni++) {
      int n = bn0 + wn + ni * 16 + lane15;
      float bv = bias[n];
      int mrow = bm0 + wm + mi * 16 + quad * 4;
      #pragma unroll
      for (int r = 0; r < 4; r++)
        C[(size_t)(mrow + r) * N + n] = (OT)(acc[mi][ni][r] + bv);
    }
}

// ------------- fused QKV GEMM + bias + RoPE + reorg (R4 epilogue) -------------
// R5 lesson: C^T fragment swap regressed (more VGPR, more bank conflicts, no
// store win) -> reverted to straight acc. R6: double-buffered prefetch K-loop
// (one barrier/iter, DMA for kt+1 in flight under compute of kt).
//   Q/K tiles: rope pairs (d, d+32) are acc[mi][p] / acc[mi][p+2] of the SAME
//     thread; rotation in f32 via tbl; store Q/K [bh][t][d] (Q pre-scaled).
//   V tiles: acc -> LDS [128][130] transpose -> blocked store
//     Vt[bh][t/64][d][t%64] (contiguous 8KB per kv tile for flash staging).
__global__ __launch_bounds__(256) void k_gemm_qkv(const half_t* __restrict__ A,
                                                  const half_t* __restrict__ Bt,
                                                  const float* __restrict__ bias,
                                                  const float2* __restrict__ tbl,
                                                  half_t* __restrict__ Qo,
                                                  half_t* __restrict__ Ko,
                                                  half_t* __restrict__ Vo) {
  __shared__ half_t smem[2][16384];        // per buf: As 8192h | Bs 8192h (64KB)
  int tid = threadIdx.x;
  int wave = tid >> 6, lane = tid & 63;
  int lane15 = lane & 15, quad = lane >> 4;
  int wm = (wave >> 1) * 64, wn = (wave & 1) * 64;
  int bm0 = blockIdx.y * 128, bn0 = blockIdx.x * 128;
  f32x4 acc[4][4] = {};

#define QKV_STAGE(bb, kb)                                                      \
  {                                                                            \
    const half_t* Ag = A + (size_t)bm0 * C_DIM + (kb);                         \
    const half_t* Bg = Bt + (size_t)bn0 * C_DIM + (kb);                        \
    _Pragma("unroll")                                                          \
    for (int p = 0; p < 4; p++) {                                              \
      int fc = wave * 4 * 64 + p * 64 + lane;                                  \
      int r = fc >> 3, c = (fc & 7) ^ (r & 7);                                 \
      load_lds16(Ag + (size_t)r * C_DIM + c * 8,                               \
                 &smem[bb][0] + (wave * 4 + p) * 512);                         \
      load_lds16(Bg + (size_t)r * C_DIM + c * 8,                               \
                 &smem[bb][8192] + (wave * 4 + p) * 512);                      \
    }                                                                          \
  }

  QKV_STAGE(0, 0);
  for (int kt = 0; kt < 16; kt++) {
    __syncthreads();                       // buf[kt&1] DMA drained & visible
    if (kt < 15) QKV_STAGE((kt + 1) & 1, (kt + 1) * 64);
    const half_t* As = &smem[kt & 1][0];
    const half_t* Bs = &smem[kt & 1][8192];
    #pragma unroll
    for (int ks = 0; ks < 2; ks++) {
      half8 af[4], bf[4];
      #pragma unroll
      for (int i = 0; i < 4; i++) {
        int Ra = wm + i * 16 + lane15;
        af[i] = *(const half8*)(As + Ra * 64 + ((ks * 4 + quad) ^ (Ra & 7)) * 8);
      }
      #pragma unroll
      for (int i = 0; i < 4; i++) {
        int Rb = wn + i * 16 + lane15;
        bf[i] = *(const half8*)(Bs + Rb * 64 + ((ks * 4 + quad) ^ (Rb & 7)) * 8);
      }
      #pragma unroll
      for (int mi = 0; mi < 4; mi++)
        #pragma unroll
        for (int ni = 0; ni < 4; ni++)
          acc[mi][ni] = __builtin_amdgcn_mfma_f32_16x16x32_f16(af[mi], bf[ni], acc[mi][ni], 0, 0, 0);
    }
  }
#undef QKV_STAGE
  // bias (b_attn) BEFORE rope, matching reference
  #pragma unroll
  for (int ni = 0; ni < 4; ni++) {
    float bv = bias[bn0 + wn + ni * 16 + lane15];
    #pragma unroll
    for (int mi = 0; mi < 4; mi++)
      #pragma unroll
      for (int r = 0; r < 4; r++) acc[mi][ni][r] += bv;
  }

  int third = bn0 >> 10;                   // 0=Q, 1=K, 2=V (block-uniform)
  if (third < 2) {
    half_t* Ob = (third == 0) ? Qo : Ko;
    int h = ((bn0 & 1023) + wn) >> 6;      // head for this wave's columns
    #pragma unroll
    for (int mi = 0; mi < 4; mi++) {
      int mrow = bm0 + wm + mi * 16 + quad * 4;
      int bq = mrow >> 11, tq = mrow & 2047;
      half_t* outp = Ob + ((size_t)(bq * 16 + h) * T_SEQ + tq) * HD;
      #pragma unroll
      for (int p = 0; p < 2; p++) {        // pair (d=j, d=j+32), j = p*16+lane15
        int j = p * 16 + lane15;
        #pragma unroll
        for (int r = 0; r < 4; r++) {
          float2 cs = tbl[(tq + r) * 32 + j];
          float a1 = acc[mi][p][r], a2 = acc[mi][p + 2][r];
          float o1 = a1 * cs.x - a2 * cs.y;
          float o2 = a1 * cs.y + a2 * cs.x;
          if (third == 0) { o1 *= QSCALE; o2 *= QSCALE; }
          outp[r * HD + j]      = (half_t)o1;
          outp[r * HD + j + 32] = (half_t)o2;
        }
      }
    }
  } else {
    // V: transpose through LDS, store blocked [bh][t/64][d][t%64]
    __syncthreads();                       // all waves done reading smem
    half_t* vt = &smem[0][0];              // [128][130], 33280B < 64KB
    #pragma unroll
    for (int mi = 0; mi < 4; mi++)
      #pragma unroll
      for (int ni = 0; ni < 4; ni++) {
        int tl = wm + mi * 16 + quad * 4, nl = wn + ni * 16 + lane15;
        #pragma unroll
        for (int r = 0; r < 4; r++)
          vt[(tl + r) * 130 + nl] = (half_t)acc[mi][ni][r];
      }
    __syncthreads();
    int hV = (bn0 - 2048) >> 6;
    int bq = bm0 >> 11, tq0 = bm0 & 2047;
    int c8 = (tid & 7) * 8;                // 8 lanes cover one 64-t row chunk
    #pragma unroll
    for (int p = 0; p < 8; p++) {
      int gr = p * 32 + (tid >> 3);        // 256 rows: (h2, d, tblk)
      int tb = gr & 1, d = (gr >> 1) & 63, h2 = gr >> 7;
      half8 vv;
      #pragma unroll
      for (int jj = 0; jj < 8; jj++)
        vv[jj] = vt[(tb * 64 + c8 + jj) * 130 + h2 * 64 + d];
      *(half8*)(Vo + ((size_t)((bq * 16 + hV + h2) * 32 + (tq0 >> 6) + tb) * 64 + d) * 64 + c8) = vv;
    }
  }
}

// ------------- causal flash v3: 128-q tiles, kv-split-2, 16 waves -------------
// 16 waves: waves 0-7 = group 0 (even kv tiles), 8-15 = group 1 (odd).
// Rounds per 128-q tile = qt+1; block does tiles x and 15-x -> 17 rounds for
// EVERY block. Grid (8,32) = 256 blocks = 1/CU, 16 waves/CU steady, no tail.
// V is kv-tile-blocked [bh][tile][d][64]: stage reads are contiguous 8KB.
template <bool DIAG>
__device__ __forceinline__ void tile_mfma(const half_t* __restrict__ Kt,
                                          const half_t* __restrict__ Vt,
                                          half8 bq0, half8 bq1,
                                          f32x4 (&ot)[4], float& l,
                                          int lane15, int quad, int qloc) {
  f32x4 sacc[4];
  #pragma unroll
  for (int s = 0; s < 4; s++) {
    int R_ = s * 16 + lane15;
    half8 ak0 = *(const half8*)(Kt + R_ * 64 + ((quad) ^ (R_ & 7)) * 8);
    half8 ak1 = *(const half8*)(Kt + R_ * 64 + ((4 + quad) ^ (R_ & 7)) * 8);
    f32x4 z = {};
    z = __builtin_amdgcn_mfma_f32_16x16x32_f16(ak0, bq0, z, 0, 0, 0);
    sacc[s] = __builtin_amdgcn_mfma_f32_16x16x32_f16(ak1, bq1, z, 0, 0, 0);
  }
  #pragma unroll
  for (int s = 0; s < 4; s++) {
    half4 bp;
    #pragma unroll
    for (int r = 0; r < 4; r++) {
      float sv = sacc[s][r];
      if (DIAG && (s * 16 + quad * 4 + r > qloc)) sv = -1.0e30f;
      float p = exp2f(fminf(sv, 14.0f));
      l += p;
      bp[r] = (half_t)p;
    }
    #pragma unroll
    for (int nm = 0; nm < 4; nm++) {
      int Rv = nm * 16 + lane15;
      half4 av = *(const half4*)(Vt + Rv * 64 +
                                 ((2 * s + (quad >> 1)) ^ (Rv & 7)) * 8 +
                                 (quad & 1) * 4);
      ot[nm] = __builtin_amdgcn_mfma_f32_16x16x16f16(av, bp, ot[nm], 0, 0, 0);
    }
  }
}

// Stage kv tiles {2t, 2t+1} of K and V into buffer bb. 1024 threads, each
// issues 1 K + 1 V load_lds16 (16B): waves 0-7 serve group 0's tile (2t),
// waves 8-15 serve group 1's tile (2t+1). 32KB total per stage.
#define STAGE(bb, t_)                                                          \
  {                                                                            \
    int gS = wave >> 3;                                                        \
    int idx = (wave & 7) * 64 + lane;                                          \
    int rr_ = idx >> 3, cc = (idx & 7) ^ (rr_ & 7);                            \
    int j = 2 * (t_) + gS;                                                     \
    load_lds16(Kb + (size_t)(j * 64 + rr_) * HD + cc * 8,                      \
               &KV[bb][0][gS][0] + idx * 8);                                   \
    load_lds16(Vb + (size_t)j * 4096 + rr_ * 64 + cc * 8,                      \
               &KV[bb][1][gS][0] + idx * 8);                                   \
  }

__device__ __forceinline__ void process_tile(
    int qt, const half_t* __restrict__ Qb, const half_t* __restrict__ Kb,
    const half_t* __restrict__ Vb, half_t* __restrict__ y, int b, int h,
    half_t (&KV)[2][2][2][4096],
    int wave, int lane, int g, int wq, int lane15, int quad) {
  int q0 = qt * 128;
  int qrow = q0 + wq * 16 + lane15;        // this wave's q column (S^T B-op n)
  half8 bq0 = *(const half8*)(Qb + (size_t)qrow * HD + quad * 8);
  half8 bq1 = *(const half8*)(Qb + (size_t)qrow * HD + 32 + quad * 8);
  f32x4 ot[4] = {};                        // O^T: d = nm*16+quad*4+r, q = lane15
  float l = 0.f;
  int R = qt + 1;                          // rounds: group g does kv tile 2r+g
  // hot loop: rounds 0..R-2, both groups unmasked
  for (int r = 0; r < R - 1; r++) {
    __syncthreads();                       // stage(r) DMA drained & visible
    STAGE((r + 1) & 1, r + 1);             // prefetch overlaps compute
    tile_mfma<false>(&KV[r & 1][0][g][0], &KV[r & 1][1][g][0], bq0, bq1, ot, l,
                     lane15, quad, 0);
  }
  // last round (r = R-1): group 0 on tile 2qt (diag for wq<4, auto-full for
  // wq>=4 since qloc>=64>srow); group 1 on tile 2qt+1 (skip wq<4, diag wq>=4)
  __syncthreads();
  {
    int buf = (R - 1) & 1;
    const half_t* Kt = &KV[buf][0][g][0];
    const half_t* Vt = &KV[buf][1][g][0];
    if (g == 0)
      tile_mfma<true>(Kt, Vt, bq0, bq1, ot, l, lane15, quad, wq * 16 + lane15);
    else if (wq >= 4)
      tile_mfma<true>(Kt, Vt, bq0, bq1, ot, l, lane15, quad,
                      (wq - 4) * 16 + lane15);
  }
  // per-wave l: sum the 4 quads holding this q-column
  l += __shfl_xor(l, 16);
  l += __shfl_xor(l, 32);
  // cross-group combine via LDS (reuse KV region, 512*17*4B = 34.8KB <= 64KB)
  __syncthreads();                         // all compute reads of K/V done
  float* cb = (float*)&KV[0][0][0][0];
  int ci = (wq * 64 + lane) * 17;          // stride 17 floats: conflict-free
  if (g == 1) {
    #pragma unroll
    for (int nm = 0; nm < 4; nm++)
      #pragma unroll
      for (int r = 0; r < 4; r++) cb[ci + nm * 4 + r] = ot[nm][r];
    cb[ci + 16] = l;
  }
  __syncthreads();
  if (g == 0) {
    #pragma unroll
    for (int nm = 0; nm < 4; nm++)
      #pragma unroll
      for (int r = 0; r < 4; r++) ot[nm][r] += cb[ci + nm * 4 + r];
    l += cb[ci + 16];
    float invl = 1.0f / l;
    int t = q0 + wq * 16 + lane15;
    half_t* yr = y + (size_t)(b * T_SEQ + t) * C_DIM + h * 64;
    #pragma unroll
    for (int nm = 0; nm < 4; nm++) {
      half4 o4;
      #pragma unroll
      for (int r = 0; r < 4; r++) o4[r] = (half_t)(ot[nm][r] * invl);
      *(half4*)(yr + nm * 16 + quad * 4) = o4;   // 8B store
    }
  }
  __syncthreads();                         // combine region free before restage
}

__global__ __launch_bounds__(1024, 4) void k_flash(const half_t* __restrict__ Qg,
                                                   const half_t* __restrict__ Kg,
                                                   const half_t* __restrict__ Vg,
                                                   half_t* __restrict__ y) {
  __shared__ half_t KV[2][2][2][4096];     // [buf][K/V][grp][64*64]
  int bh = blockIdx.y;
  int b = bh >> 4, h = bh & 15;
  int x = blockIdx.x;                      // 0..7: q-tile pair (x, 15-x)
  int tid = threadIdx.x;
  int wave = tid >> 6, lane = tid & 63;
  int g = wave >> 3, wq = wave & 7;        // kv-parity group, q-warp in group
  int lane15 = lane & 15, quad = lane >> 4;
  const half_t* Qb = Qg + (size_t)bh * T_SEQ * HD;
  const half_t* Kb = Kg + (size_t)bh * T_SEQ * HD;
  const half_t* Vb = Vg + (size_t)bh * HD * T_SEQ;

  int qtA = x, qtB = 15 - x;
  STAGE(0, 0);
  process_tile(qtA, Qb, Kb, Vb, y, b, h, KV, wave, lane, g, wq, lane15, quad);
  STAGE(0, 0);                             // one un-overlapped stage per block
  process_tile(qtB, Qb, Kb, Vb, y, b, h, KV, wave, lane, g, wq, lane15, quad);
  #undef STAGE
}

extern "C" void kernel_launch(void* const* d_in, const int* in_sizes, int n_in,
                              void* d_out, int out_size, void* d_ws, size_t ws_size,
                              hipStream_t stream) {
  const float* x      = (const float*)d_in[0];
  const float* w_attn = (const float*)d_in[1];
  const float* b_attn = (const float*)d_in[2];
  const float* w_proj = (const float*)d_in[3];
  const float* b_proj = (const float*)d_in[4];
  float* out = (float*)d_out;

  char* ws = (char*)d_ws;
  const size_t MB = 1u << 20;
  half_t* xb  = (half_t*)(ws);             // 8 MB  x in f16
  half_t* wT  = (half_t*)(ws + 8 * MB);    // 6 MB  w_attn^T f16 [3072][1024]
  half_t* wpT = (half_t*)(ws + 14 * MB);   // 2 MB  w_proj^T f16 [1024][1024]
  half_t* Q   = (half_t*)(ws + 16 * MB);   // 8 MB  [bh][t][d]  (pre-scaled)
  half_t* Kb  = (half_t*)(ws + 24 * MB);   // 8 MB  [bh][t][d]
  half_t* Vt  = (half_t*)(ws + 32 * MB);   // 8 MB  [bh][t/64][d][t%64] blocked
  half_t* y   = (half_t*)(ws + 40 * MB);   // 8 MB  attn out f16
  float2* tbl = (float2*)(ws + 48 * MB);   // 512KB rope table [2048][32]

  k_prep<<<4096 + 768 + 256 + 256, 256, 0, stream>>>(x, xb, w_attn, wT,
                                                     w_proj, wpT, tbl);
  k_gemm_qkv<<<dim3(N_QKV / 128, M_ROWS / 128), 256, 0, stream>>>(
      xb, wT, b_attn, tbl, Q, Kb, Vt);
  k_flash<<<dim3(8, B_SZ * N_HEADS), 1024, 0, stream>>>(Q, Kb, Vt, y);
  k_gemm<float, 64><<<dim3(C_DIM / 64, M_ROWS / 128), 256, 0, stream>>>(
      y, wpT, b_proj, out, M_ROWS, C_DIM, C_DIM);
}

// Round 8
// 183.547 us; speedup vs baseline: 1.0352x; 1.0035x over previous
//
#include <hip/hip_runtime.h>
#include <hip/hip_bf16.h>
#include <cmath>

typedef _Float16 half_t;
typedef half_t half4 __attribute__((ext_vector_type(4)));
typedef half_t half8 __attribute__((ext_vector_type(8)));
typedef float f32x4 __attribute__((ext_vector_type(4)));

#define N_HEADS 16
#define HD      64
#define T_SEQ   2048
#define B_SZ    2
#define C_DIM   1024
#define M_ROWS  (B_SZ * T_SEQ)   /* 4096 */
#define N_QKV   (3 * C_DIM)      /* 3072 */
#define QSCALE  0.18033688f      /* 0.125 * log2(e), folded into Q at rope */

__device__ inline void load_lds16(const half_t* g, half_t* l) {
  __builtin_amdgcn_global_load_lds(
      (const __attribute__((address_space(1))) void*)g,
      (__attribute__((address_space(3))) void*)l, 16, 0, 0);
}

// ---- fused prep: x->f16 (0..4095), w_attn^T (..4863), w_proj^T (..5119),
// ---- rope cos/sin table (5120..5375): tbl[t][j] = {cos,sin}(t*10000^(-j/32))
__global__ __launch_bounds__(256) void k_prep(const float* __restrict__ x,
                                              half_t* __restrict__ xb,
                                              const float* __restrict__ wa,
                                              half_t* __restrict__ wT,
                                              const float* __restrict__ wp,
                                              half_t* __restrict__ wpT,
                                              float2* __restrict__ tbl) {
  __shared__ float tile[64][65];
  int bid = blockIdx.x, tid = threadIdx.x;
  if (bid < 4096) {
    int i = (bid * 256 + tid) * 4;
    float4 v = *(const float4*)(x + i);
    half_t o[4] = {(half_t)v.x, (half_t)v.y, (half_t)v.z, (half_t)v.w};
    *(ulong1*)(xb + i) = *(ulong1*)o;
    return;
  }
  if (bid >= 5120) {                       // rope table: 65536 entries
    int idx = (bid - 5120) * 256 + tid;
    int t = idx >> 5, j = idx & 31;
    float inv = exp2f(-(float)j * (13.287712379549449f / 32.0f));
    float s, c;
    sincosf((float)t * inv, &s, &c);
    tbl[idx] = make_float2(c, s);
    return;
  }
  const float* in; half_t* out; int K, N, id;
  if (bid < 4864) { id = bid - 4096; in = wa; out = wT;  K = 1024; N = 3072; }
  else            { id = bid - 4864; in = wp; out = wpT; K = 1024; N = 1024; }
  int n0 = (id % (N / 64)) * 64, k0 = (id / (N / 64)) * 64;
  int tx = tid & 63, ty = tid >> 6;
  #pragma unroll
  for (int i = 0; i < 64; i += 4)
    tile[ty + i][tx] = in[(size_t)(k0 + ty + i) * N + n0 + tx];
  __syncthreads();
  #pragma unroll
  for (int i = 0; i < 64; i += 4) {
    int r = ty + i;
    out[(size_t)(n0 + r) * K + k0 + tx] = (half_t)tile[tx][r];
  }
}

// ------------- GEMM: C = A(f16,[M][K]) * Bt(f16,[N][K])^T + bias, OT out ----
// 128xTN tile, BK=64, double-buffered prefetch (one barrier per K-iter).
template <typename OT, int TN>
__global__ __launch_bounds__(256) void k_gemm(const half_t* __restrict__ A,
                                              const half_t* __restrict__ Bt,
                                              const float* __restrict__ bias,
                                              OT* __restrict__ C,
                                              int M, int N, int K) {
  constexpr int NI = TN / 32;          // n-fragments per wave
  __shared__ half_t As[2][128 * 64];
  __shared__ half_t Bs[2][TN * 64];
  int tid = threadIdx.x;
  int wave = tid >> 6, lane = tid & 63;
  int lane15 = lane & 15, quad = lane >> 4;
  int wm = (wave >> 1) * 64, wn = (wave & 1) * (TN / 2);
  int bm0 = blockIdx.y * 128, bn0 = blockIdx.x * TN;
  f32x4 acc[4][NI] = {};

#define G_STAGE(bb, kb)                                                        \
  {                                                                            \
    const half_t* Ag = A + (size_t)bm0 * K + (kb);                             \
    const half_t* Bg = Bt + (size_t)bn0 * K + (kb);                            \
    _Pragma("unroll")                                                          \
    for (int p = 0; p < 4; p++) {                                              \
      int fc = wave * 4 * 64 + p * 64 + lane;                                  \
      int r = fc >> 3, c = (fc & 7) ^ (r & 7);                                 \
      load_lds16(Ag + (size_t)r * K + c * 8, &As[bb][0] + (wave * 4 + p) * 512); \
    }                                                                          \
    _Pragma("unroll")                                                          \
    for (int p = 0; p < NI; p++) {                                             \
      int fc = wave * NI * 64 + p * 64 + lane;                                 \
      int r = fc >> 3, c = (fc & 7) ^ (r & 7);                                 \
      load_lds16(Bg + (size_t)r * K + c * 8, &Bs[bb][0] + (wave * NI + p) * 512); \
    }                                                                          \
  }

  G_STAGE(0, 0);
  int NT = K / 64;
  for (int kt = 0; kt < NT; kt++) {
    __syncthreads();                       // buf[kt&1] DMA drained & visible
    if (kt + 1 < NT) G_STAGE((kt + 1) & 1, (kt + 1) * 64);
    const half_t* Asb = &As[kt & 1][0];
    const half_t* Bsb = &Bs[kt & 1][0];
    #pragma unroll
    for (int ks = 0; ks < 2; ks++) {
      half8 af[4], bf[NI];
      #pragma unroll
      for (int i = 0; i < 4; i++) {
        int Ra = wm + i * 16 + lane15;
        af[i] = *(const half8*)(Asb + Ra * 64 + ((ks * 4 + quad) ^ (Ra & 7)) * 8);
      }
      #pragma unroll
      for (int i = 0; i < NI; i++) {
        int Rb = wn + i * 16 + lane15;
        bf[i] = *(const half8*)(Bsb + Rb * 64 + ((ks * 4 + quad) ^ (Rb & 7)) * 8);
      }
      #pragma unroll
      for (int mi = 0; mi < 4; mi++)
        #pragma unroll
        for (int ni = 0; ni < NI; ni++)
          acc[mi][ni] = __builtin_amdgcn_mfma_f32_16x16x32_f16(af[mi], bf[ni], acc[mi][ni], 0, 0, 0);
    }
  }
#undef G_STAGE
  #pragma unroll
  for (int mi = 0; mi < 4; mi++)
    #pragma unroll
    for (int ni = 0; ni < NI; ni++) {
      int n = bn0 + wn + ni * 16 + lane15;
      float bv = bias[n];
      int mrow = bm0 + wm + mi * 16 + quad * 4;
      #pragma unroll
      for (int r = 0; r < 4; r++)
        C[(size_t)(mrow + r) * N + n] = (OT)(acc[mi][ni][r] + bv);
    }
}

// ------------- fused QKV GEMM + bias + RoPE + reorg (R4 epilogue, R6 dbuf) ----
__global__ __launch_bounds__(256) void k_gemm_qkv(const half_t* __restrict__ A,
                                                  const half_t* __restrict__ Bt,
                                                  const float* __restrict__ bias,
                                                  const float2* __restrict__ tbl,
                                                  half_t* __restrict__ Qo,
                                                  half_t* __restrict__ Ko,
                                                  half_t* __restrict__ Vo) {
  __shared__ half_t smem[2][16384];        // per buf: As 8192h | Bs 8192h (64KB)
  int tid = threadIdx.x;
  int wave = tid >> 6, lane = tid & 63;
  int lane15 = lane & 15, quad = lane >> 4;
  int wm = (wave >> 1) * 64, wn = (wave & 1) * 64;
  int bm0 = blockIdx.y * 128, bn0 = blockIdx.x * 128;
  f32x4 acc[4][4] = {};

#define QKV_STAGE(bb, kb)                                                      \
  {                                                                            \
    const half_t* Ag = A + (size_t)bm0 * C_DIM + (kb);                         \
    const half_t* Bg = Bt + (size_t)bn0 * C_DIM + (kb);                        \
    _Pragma("unroll")                                                          \
    for (int p = 0; p < 4; p++) {                                              \
      int fc = wave * 4 * 64 + p * 64 + lane;                                  \
      int r = fc >> 3, c = (fc & 7) ^ (r & 7);                                 \
      load_lds16(Ag + (size_t)r * C_DIM + c * 8,                               \
                 &smem[bb][0] + (wave * 4 + p) * 512);                         \
      load_lds16(Bg + (size_t)r * C_DIM + c * 8,                               \
                 &smem[bb][8192] + (wave * 4 + p) * 512);                      \
    }                                                                          \
  }

  QKV_STAGE(0, 0);
  for (int kt = 0; kt < 16; kt++) {
    __syncthreads();                       // buf[kt&1] DMA drained & visible
    if (kt < 15) QKV_STAGE((kt + 1) & 1, (kt + 1) * 64);
    const half_t* As = &smem[kt & 1][0];
    const half_t* Bs = &smem[kt & 1][8192];
    #pragma unroll
    for (int ks = 0; ks < 2; ks++) {
      half8 af[4], bf[4];
      #pragma unroll
      for (int i = 0; i < 4; i++) {
        int Ra = wm + i * 16 + lane15;
        af[i] = *(const half8*)(As + Ra * 64 + ((ks * 4 + quad) ^ (Ra & 7)) * 8);
      }
      #pragma unroll
      for (int i = 0; i < 4; i++) {
        int Rb = wn + i * 16 + lane15;
        bf[i] = *(const half8*)(Bs + Rb * 64 + ((ks * 4 + quad) ^ (Rb & 7)) * 8);
      }
      #pragma unroll
      for (int mi = 0; mi < 4; mi++)
        #pragma unroll
        for (int ni = 0; ni < 4; ni++)
          acc[mi][ni] = __builtin_amdgcn_mfma_f32_16x16x32_f16(af[mi], bf[ni], acc[mi][ni], 0, 0, 0);
    }
  }
#undef QKV_STAGE
  // bias (b_attn) BEFORE rope, matching reference
  #pragma unroll
  for (int ni = 0; ni < 4; ni++) {
    float bv = bias[bn0 + wn + ni * 16 + lane15];
    #pragma unroll
    for (int mi = 0; mi < 4; mi++)
      #pragma unroll
      for (int r = 0; r < 4; r++) acc[mi][ni][r] += bv;
  }

  int third = bn0 >> 10;                   // 0=Q, 1=K, 2=V (block-uniform)
  if (third < 2) {
    half_t* Ob = (third == 0) ? Qo : Ko;
    int h = ((bn0 & 1023) + wn) >> 6;      // head for this wave's columns
    #pragma unroll
    for (int mi = 0; mi < 4; mi++) {
      int mrow = bm0 + wm + mi * 16 + quad * 4;
      int bq = mrow >> 11, tq = mrow & 2047;
      half_t* outp = Ob + ((size_t)(bq * 16 + h) * T_SEQ + tq) * HD;
      #pragma unroll
      for (int p = 0; p < 2; p++) {        // pair (d=j, d=j+32), j = p*16+lane15
        int j = p * 16 + lane15;
        #pragma unroll
        for (int r = 0; r < 4; r++) {
          float2 cs = tbl[(tq + r) * 32 + j];
          float a1 = acc[mi][p][r], a2 = acc[mi][p + 2][r];
          float o1 = a1 * cs.x - a2 * cs.y;
          float o2 = a1 * cs.y + a2 * cs.x;
          if (third == 0) { o1 *= QSCALE; o2 *= QSCALE; }
          outp[r * HD + j]      = (half_t)o1;
          outp[r * HD + j + 32] = (half_t)o2;
        }
      }
    }
  } else {
    // V: transpose through LDS, store blocked [bh][t/64][d][t%64]
    __syncthreads();                       // all waves done reading smem
    half_t* vt = &smem[0][0];              // [128][130], 33280B < 64KB
    #pragma unroll
    for (int mi = 0; mi < 4; mi++)
      #pragma unroll
      for (int ni = 0; ni < 4; ni++) {
        int tl = wm + mi * 16 + quad * 4, nl = wn + ni * 16 + lane15;
        #pragma unroll
        for (int r = 0; r < 4; r++)
          vt[(tl + r) * 130 + nl] = (half_t)acc[mi][ni][r];
      }
    __syncthreads();
    int hV = (bn0 - 2048) >> 6;
    int bq = bm0 >> 11, tq0 = bm0 & 2047;
    int c8 = (tid & 7) * 8;                // 8 lanes cover one 64-t row chunk
    #pragma unroll
    for (int p = 0; p < 8; p++) {
      int gr = p * 32 + (tid >> 3);        // 256 rows: (h2, d, tblk)
      int tb = gr & 1, d = (gr >> 1) & 63, h2 = gr >> 7;
      half8 vv;
      #pragma unroll
      for (int jj = 0; jj < 8; jj++)
        vv[jj] = vt[(tb * 64 + c8 + jj) * 130 + h2 * 64 + d];
      *(half8*)(Vo + ((size_t)((bq * 16 + hV + h2) * 32 + (tq0 >> 6) + tb) * 64 + d) * 64 + c8) = vv;
    }
  }
}

// ------------- causal flash v4: merged q-tile pair + XCD colocation -------------
// R7 counters: 51% of 139MB issued staging missed L2 (FETCH 71.5MB) because
// the 8 blocks sharing a bh round-robin across XCDs (XCD = flat%8 assumed) ->
// each 4MB L2 sees all 32 bh of K/V (32MB). Fix 1: swizzle so all 8 blocks of
// one bh share flat%8 -> per-XCD K/V working set 4MB = L2-resident.
// Fix 2: merge the (x, 15-x) q-tile pair into ONE kv sweep: stage each kv tile
// once (32-2x tiles) and apply to both q-tiles while active. Issued staging
// 139MB -> 102MB; uniform 17 tile-units of compute per wave; no mid-block
// un-overlapped stage. Diagonal masks reuse the v3 per-parity-group pattern.
template <bool DIAG>
__device__ __forceinline__ void tile_mfma(const half_t* __restrict__ Kt,
                                          const half_t* __restrict__ Vt,
                                          half8 bq0, half8 bq1,
                                          f32x4 (&ot)[4], float& l,
                                          int lane15, int quad, int qloc) {
  f32x4 sacc[4];
  #pragma unroll
  for (int s = 0; s < 4; s++) {
    int R_ = s * 16 + lane15;
    half8 ak0 = *(const half8*)(Kt + R_ * 64 + ((quad) ^ (R_ & 7)) * 8);
    half8 ak1 = *(const half8*)(Kt + R_ * 64 + ((4 + quad) ^ (R_ & 7)) * 8);
    f32x4 z = {};
    z = __builtin_amdgcn_mfma_f32_16x16x32_f16(ak0, bq0, z, 0, 0, 0);
    sacc[s] = __builtin_amdgcn_mfma_f32_16x16x32_f16(ak1, bq1, z, 0, 0, 0);
  }
  #pragma unroll
  for (int s = 0; s < 4; s++) {
    half4 bp;
    #pragma unroll
    for (int r = 0; r < 4; r++) {
      float sv = sacc[s][r];
      if (DIAG && (s * 16 + quad * 4 + r > qloc)) sv = -1.0e30f;
      float p = exp2f(fminf(sv, 14.0f));
      l += p;
      bp[r] = (half_t)p;
    }
    #pragma unroll
    for (int nm = 0; nm < 4; nm++) {
      int Rv = nm * 16 + lane15;
      half4 av = *(const half4*)(Vt + Rv * 64 +
                                 ((2 * s + (quad >> 1)) ^ (Rv & 7)) * 8 +
                                 (quad & 1) * 4);
      ot[nm] = __builtin_amdgcn_mfma_f32_16x16x16f16(av, bp, ot[nm], 0, 0, 0);
    }
  }
}

// Stage kv tiles {2t, 2t+1} of K and V into buffer bb. 1024 threads, each
// issues 1 K + 1 V load_lds16 (16B): waves 0-7 serve tile 2t, waves 8-15
// tile 2t+1. 32KB total per stage.
#define STAGE(bb, t_)                                                          \
  {                                                                            \
    int gS = wave >> 3;                                                        \
    int idx = (wave & 7) * 64 + lane;                                          \
    int rr_ = idx >> 3, cc = (idx & 7) ^ (rr_ & 7);                            \
    int j = 2 * (t_) + gS;                                                     \
    load_lds16(Kb + (size_t)(j * 64 + rr_) * HD + cc * 8,                      \
               &KV[bb][0][gS][0] + idx * 8);                                   \
    load_lds16(Vb + (size_t)j * 4096 + rr_ * 64 + cc * 8,                      \
               &KV[bb][1][gS][0] + idx * 8);                                   \
  }

__global__ __launch_bounds__(1024, 4) void k_flash(const half_t* __restrict__ Qg,
                                                   const half_t* __restrict__ Kg,
                                                   const half_t* __restrict__ Vg,
                                                   half_t* __restrict__ y) {
  __shared__ half_t KV[2][2][2][4096];     // [buf][K/V][parity][64*64]
  // XCD-colocation swizzle (assumes XCD = flat % 8, round-robin dispatch):
  // all 8 blocks of one bh get the same flat%8 -> same XCD -> K/V L2-resident.
  int flat = (int)blockIdx.x + 8 * (int)blockIdx.y;
  int x  = (flat >> 3) & 7;                // q-tile pair id 0..7
  int bh = (flat & 7) | ((flat >> 6) << 3);
  int b = bh >> 4, h = bh & 15;
  int tid = threadIdx.x;
  int wave = tid >> 6, lane = tid & 63;
  int g = wave >> 3, wq = wave & 7;        // kv-parity group, q-warp in group
  int lane15 = lane & 15, quad = lane >> 4;
  const half_t* Qb = Qg + (size_t)bh * T_SEQ * HD;
  const half_t* Kb = Kg + (size_t)bh * T_SEQ * HD;
  const half_t* Vb = Vg + (size_t)bh * HD * T_SEQ;

  int qtA = x, qtB = 15 - x;               // A < B always
  int jA = 2 * qtA, jB = 2 * qtB;          // diagonal kv-tile bases
  int qlA = qtA * 128 + wq * 16 + lane15;
  int qlB = qtB * 128 + wq * 16 + lane15;
  half8 aq0 = *(const half8*)(Qb + (size_t)qlA * HD + quad * 8);
  half8 aq1 = *(const half8*)(Qb + (size_t)qlA * HD + 32 + quad * 8);
  half8 bq0 = *(const half8*)(Qb + (size_t)qlB * HD + quad * 8);
  half8 bq1 = *(const half8*)(Qb + (size_t)qlB * HD + 32 + quad * 8);
  f32x4 otA[4] = {}, otB[4] = {};
  float lA = 0.f, lB = 0.f;

  int R = 16 - x;                          // rounds; round r stages tiles 2r,2r+1
  STAGE(0, 0);
  for (int r = 0; r < R; r++) {
    __syncthreads();                       // stage(r) DMA drained & visible
    if (r + 1 < R) STAGE((r + 1) & 1, r + 1);  // prefetch overlaps compute
    const half_t* Kt = &KV[r & 1][0][g][0];
    const half_t* Vt = &KV[r & 1][1][g][0];
    int j = 2 * r + g;                     // this group's kv tile
    // tile A (q rows 128x..128x+127): active while j <= jA+1
    if (j < jA)
      tile_mfma<false>(Kt, Vt, aq0, aq1, otA, lA, lane15, quad, 0);
    else if (j == jA)                      // parity 0 -> group 0 only
      tile_mfma<true>(Kt, Vt, aq0, aq1, otA, lA, lane15, quad,
                      wq * 16 + lane15);
    else if (j == jA + 1 && wq >= 4)       // parity 1 -> group 1; wq<4 all-masked
      tile_mfma<true>(Kt, Vt, aq0, aq1, otA, lA, lane15, quad,
                      (wq - 4) * 16 + lane15);
    // tile B (q rows 128(15-x)..): active while j <= jB+1
    if (j < jB)
      tile_mfma<false>(Kt, Vt, bq0, bq1, otB, lB, lane15, quad, 0);
    else if (j == jB)
      tile_mfma<true>(Kt, Vt, bq0, bq1, otB, lB, lane15, quad,
                      wq * 16 + lane15);
    else if (j == jB + 1 && wq >= 4)
      tile_mfma<true>(Kt, Vt, bq0, bq1, otB, lB, lane15, quad,
                      (wq - 4) * 16 + lane15);
  }
  // per-wave l: sum the 4 quads holding each q-column
  lA += __shfl_xor(lA, 16); lA += __shfl_xor(lA, 32);
  lB += __shfl_xor(lB, 16); lB += __shfl_xor(lB, 32);
  // cross-group combine via LDS (reuse KV region, 512*17*4B = 34.8KB <= 64KB)
  float* cb = (float*)&KV[0][0][0][0];
  int ci = (wq * 64 + lane) * 17;          // stride 17 floats: conflict-free
  // ---- tile A ----
  __syncthreads();                         // all K/V reads done; region free
  if (g == 1) {
    #pragma unroll
    for (int nm = 0; nm < 4; nm++)
      #pragma unroll
      for (int r = 0; r < 4; r++) cb[ci + nm * 4 + r] = otA[nm][r];
    cb[ci + 16] = lA;
  }
  __syncthreads();
  if (g == 0) {
    #pragma unroll
    for (int nm = 0; nm < 4; nm++)
      #pragma unroll
      for (int r = 0; r < 4; r++) otA[nm][r] += cb[ci + nm * 4 + r];
    lA += cb[ci + 16];
    float invl = 1.0f / lA;
    int t = qtA * 128 + wq * 16 + lane15;
    half_t* yr = y + (size_t)(b * T_SEQ + t) * C_DIM + h * 64;
    #pragma unroll
    for (int nm = 0; nm < 4; nm++) {
      half4 o4;
      #pragma unroll
      for (int r = 0; r < 4; r++) o4[r] = (half_t)(otA[nm][r] * invl);
      *(half4*)(yr + nm * 16 + quad * 4) = o4;   // 8B store
    }
  }
  // ---- tile B ----
  __syncthreads();
  if (g == 1) {
    #pragma unroll
    for (int nm = 0; nm < 4; nm++)
      #pragma unroll
      for (int r = 0; r < 4; r++) cb[ci + nm * 4 + r] = otB[nm][r];
    cb[ci + 16] = lB;
  }
  __syncthreads();
  if (g == 0) {
    #pragma unroll
    for (int nm = 0; nm < 4; nm++)
      #pragma unroll
      for (int r = 0; r < 4; r++) otB[nm][r] += cb[ci + nm * 4 + r];
    lB += cb[ci + 16];
    float invl = 1.0f / lB;
    int t = qtB * 128 + wq * 16 + lane15;
    half_t* yr = y + (size_t)(b * T_SEQ + t) * C_DIM + h * 64;
    #pragma unroll
    for (int nm = 0; nm < 4; nm++) {
      half4 o4;
      #pragma unroll
      for (int r = 0; r < 4; r++) o4[r] = (half_t)(otB[nm][r] * invl);
      *(half4*)(yr + nm * 16 + quad * 4) = o4;   // 8B store
    }
  }
  #undef STAGE
}

extern "C" void kernel_launch(void* const* d_in, const int* in_sizes, int n_in,
                              void* d_out, int out_size, void* d_ws, size_t ws_size,
                              hipStream_t stream) {
  const float* x      = (const float*)d_in[0];
  const float* w_attn = (const float*)d_in[1];
  const float* b_attn = (const float*)d_in[2];
  const float* w_proj = (const float*)d_in[3];
  const float* b_proj = (const float*)d_in[4];
  float* out = (float*)d_out;

  char* ws = (char*)d_ws;
  const size_t MB = 1u << 20;
  half_t* xb  = (half_t*)(ws);             // 8 MB  x in f16
  half_t* wT  = (half_t*)(ws + 8 * MB);    // 6 MB  w_attn^T f16 [3072][1024]
  half_t* wpT = (half_t*)(ws + 14 * MB);   // 2 MB  w_proj^T f16 [1024][1024]
  half_t* Q   = (half_t*)(ws + 16 * MB);   // 8 MB  [bh][t][d]  (pre-scaled)
  half_t* Kb  = (half_t*)(ws + 24 * MB);   // 8 MB  [bh][t][d]
  half_t* Vt  = (half_t*)(ws + 32 * MB);   // 8 MB  [bh][t/64][d][t%64] blocked
  half_t* y   = (half_t*)(ws + 40 * MB);   // 8 MB  attn out f16
  float2* tbl = (float2*)(ws + 48 * MB);   // 512KB rope table [2048][32]

  k_prep<<<4096 + 768 + 256 + 256, 256, 0, stream>>>(x, xb, w_attn, wT,
                                                     w_proj, wpT, tbl);
  k_gemm_qkv<<<dim3(N_QKV / 128, M_ROWS / 128), 256, 0, stream>>>(
      xb, wT, b_attn, tbl, Q, Kb, Vt);
  k_flash<<<dim3(8, B_SZ * N_HEADS), 1024, 0, stream>>>(Q, Kb, Vt, y);
  k_gemm<float, 64><<<dim3(C_DIM / 64, M_ROWS / 128), 256, 0, stream>>>(
      y, wpT, b_proj, out, M_ROWS, C_DIM, C_DIM);
}

// Round 10
// 177.248 us; speedup vs baseline: 1.0720x; 1.0355x over previous
//
#include <hip/hip_runtime.h>
#include <hip/hip_bf16.h>
#include <cmath>

typedef _Float16 half_t;
typedef half_t half4 __attribute__((ext_vector_type(4)));
typedef half_t half8 __attribute__((ext_vector_type(8)));
typedef float f32x4 __attribute__((ext_vector_type(4)));

#define N_HEADS 16
#define HD      64
#define T_SEQ   2048
#define B_SZ    2
#define C_DIM   1024
#define M_ROWS  (B_SZ * T_SEQ)   /* 4096 */
#define N_QKV   (3 * C_DIM)      /* 3072 */
#define QSCALE  0.18033688f      /* 0.125 * log2(e), folded into Q at rope */

__device__ inline void load_lds16(const half_t* g, half_t* l) {
  __builtin_amdgcn_global_load_lds(
      (const __attribute__((address_space(1))) void*)g,
      (__attribute__((address_space(3))) void*)l, 16, 0, 0);
}

// ---- fused prep: x->f16 (0..4095), w_attn^T (..4863), w_proj^T (..5119),
// ---- rope cos/sin table (5120..5375): tbl[t][j] = {cos,sin}(t*10000^(-j/32))
__global__ __launch_bounds__(256) void k_prep(const float* __restrict__ x,
                                              half_t* __restrict__ xb,
                                              const float* __restrict__ wa,
                                              half_t* __restrict__ wT,
                                              const float* __restrict__ wp,
                                              half_t* __restrict__ wpT,
                                              float2* __restrict__ tbl) {
  __shared__ float tile[64][65];
  int bid = blockIdx.x, tid = threadIdx.x;
  if (bid < 4096) {
    int i = (bid * 256 + tid) * 4;
    float4 v = *(const float4*)(x + i);
    half_t o[4] = {(half_t)v.x, (half_t)v.y, (half_t)v.z, (half_t)v.w};
    *(ulong1*)(xb + i) = *(ulong1*)o;
    return;
  }
  if (bid >= 5120) {                       // rope table: 65536 entries
    int idx = (bid - 5120) * 256 + tid;
    int t = idx >> 5, j = idx & 31;
    float inv = exp2f(-(float)j * (13.287712379549449f / 32.0f));
    float s, c;
    sincosf((float)t * inv, &s, &c);
    tbl[idx] = make_float2(c, s);
    return;
  }
  const float* in; half_t* out; int K, N, id;
  if (bid < 4864) { id = bid - 4096; in = wa; out = wT;  K = 1024; N = 3072; }
  else            { id = bid - 4864; in = wp; out = wpT; K = 1024; N = 1024; }
  int n0 = (id % (N / 64)) * 64, k0 = (id / (N / 64)) * 64;
  int tx = tid & 63, ty = tid >> 6;
  #pragma unroll
  for (int i = 0; i < 64; i += 4)
    tile[ty + i][tx] = in[(size_t)(k0 + ty + i) * N + n0 + tx];
  __syncthreads();
  #pragma unroll
  for (int i = 0; i < 64; i += 4) {
    int r = ty + i;
    out[(size_t)(n0 + r) * K + k0 + tx] = (half_t)tile[tx][r];
  }
}

// ------------- GEMM: C = A(f16,[M][K]) * Bt(f16,[N][K])^T + bias, OT out ----
// 128xTN tile, BK=64, double-buffered prefetch (one barrier per K-iter).
template <typename OT, int TN>
__global__ __launch_bounds__(256) void k_gemm(const half_t* __restrict__ A,
                                              const half_t* __restrict__ Bt,
                                              const float* __restrict__ bias,
                                              OT* __restrict__ C,
                                              int M, int N, int K) {
  constexpr int NI = TN / 32;          // n-fragments per wave
  __shared__ half_t As[2][128 * 64];
  __shared__ half_t Bs[2][TN * 64];
  int tid = threadIdx.x;
  int wave = tid >> 6, lane = tid & 63;
  int lane15 = lane & 15, quad = lane >> 4;
  int wm = (wave >> 1) * 64, wn = (wave & 1) * (TN / 2);
  int bm0 = blockIdx.y * 128, bn0 = blockIdx.x * TN;
  f32x4 acc[4][NI] = {};

#define G_STAGE(bb, kb)                                                        \
  {                                                                            \
    const half_t* Ag = A + (size_t)bm0 * K + (kb);                             \
    const half_t* Bg = Bt + (size_t)bn0 * K + (kb);                            \
    _Pragma("unroll")                                                          \
    for (int p = 0; p < 4; p++) {                                              \
      int fc = wave * 4 * 64 + p * 64 + lane;                                  \
      int r = fc >> 3, c = (fc & 7) ^ (r & 7);                                 \
      load_lds16(Ag + (size_t)r * K + c * 8, &As[bb][0] + (wave * 4 + p) * 512); \
    }                                                                          \
    _Pragma("unroll")                                                          \
    for (int p = 0; p < NI; p++) {                                             \
      int fc = wave * NI * 64 + p * 64 + lane;                                 \
      int r = fc >> 3, c = (fc & 7) ^ (r & 7);                                 \
      load_lds16(Bg + (size_t)r * K + c * 8, &Bs[bb][0] + (wave * NI + p) * 512); \
    }                                                                          \
  }

  G_STAGE(0, 0);
  int NT = K / 64;
  for (int kt = 0; kt < NT; kt++) {
    __syncthreads();                       // buf[kt&1] DMA drained & visible
    if (kt + 1 < NT) G_STAGE((kt + 1) & 1, (kt + 1) * 64);
    const half_t* Asb = &As[kt & 1][0];
    const half_t* Bsb = &Bs[kt & 1][0];
    #pragma unroll
    for (int ks = 0; ks < 2; ks++) {
      half8 af[4], bf[NI];
      #pragma unroll
      for (int i = 0; i < 4; i++) {
        int Ra = wm + i * 16 + lane15;
        af[i] = *(const half8*)(Asb + Ra * 64 + ((ks * 4 + quad) ^ (Ra & 7)) * 8);
      }
      #pragma unroll
      for (int i = 0; i < NI; i++) {
        int Rb = wn + i * 16 + lane15;
        bf[i] = *(const half8*)(Bsb + Rb * 64 + ((ks * 4 + quad) ^ (Rb & 7)) * 8);
      }
      #pragma unroll
      for (int mi = 0; mi < 4; mi++)
        #pragma unroll
        for (int ni = 0; ni < NI; ni++)
          acc[mi][ni] = __builtin_amdgcn_mfma_f32_16x16x32_f16(af[mi], bf[ni], acc[mi][ni], 0, 0, 0);
    }
  }
#undef G_STAGE
  #pragma unroll
  for (int mi = 0; mi < 4; mi++)
    #pragma unroll
    for (int ni = 0; ni < NI; ni++) {
      int n = bn0 + wn + ni * 16 + lane15;
      float bv = bias[n];
      int mrow = bm0 + wm + mi * 16 + quad * 4;
      #pragma unroll
      for (int r = 0; r < 4; r++)
        C[(size_t)(mrow + r) * N + n] = (OT)(acc[mi][ni][r] + bv);
    }
}

// ------------- fused QKV GEMM + bias + RoPE + reorg (R4 epilogue, R6 dbuf) ----
__global__ __launch_bounds__(256) void k_gemm_qkv(const half_t* __restrict__ A,
                                                  const half_t* __restrict__ Bt,
                                                  const float* __restrict__ bias,
                                                  const float2* __restrict__ tbl,
                                                  half_t* __restrict__ Qo,
                                                  half_t* __restrict__ Ko,
                                                  half_t* __restrict__ Vo) {
  __shared__ half_t smem[2][16384];        // per buf: As 8192h | Bs 8192h (64KB)
  int tid = threadIdx.x;
  int wave = tid >> 6, lane = tid & 63;
  int lane15 = lane & 15, quad = lane >> 4;
  int wm = (wave >> 1) * 64, wn = (wave & 1) * 64;
  int bm0 = blockIdx.y * 128, bn0 = blockIdx.x * 128;
  f32x4 acc[4][4] = {};

#define QKV_STAGE(bb, kb)                                                      \
  {                                                                            \
    const half_t* Ag = A + (size_t)bm0 * C_DIM + (kb);                         \
    const half_t* Bg = Bt + (size_t)bn0 * C_DIM + (kb);                        \
    _Pragma("unroll")                                                          \
    for (int p = 0; p < 4; p++) {                                              \
      int fc = wave * 4 * 64 + p * 64 + lane;                                  \
      int r = fc >> 3, c = (fc & 7) ^ (r & 7);                                 \
      load_lds16(Ag + (size_t)r * C_DIM + c * 8,                               \
                 &smem[bb][0] + (wave * 4 + p) * 512);                         \
      load_lds16(Bg + (size_t)r * C_DIM + c * 8,                               \
                 &smem[bb][8192] + (wave * 4 + p) * 512);                      \
    }                                                                          \
  }

  QKV_STAGE(0, 0);
  for (int kt = 0; kt < 16; kt++) {
    __syncthreads();                       // buf[kt&1] DMA drained & visible
    if (kt < 15) QKV_STAGE((kt + 1) & 1, (kt + 1) * 64);
    const half_t* As = &smem[kt & 1][0];
    const half_t* Bs = &smem[kt & 1][8192];
    #pragma unroll
    for (int ks = 0; ks < 2; ks++) {
      half8 af[4], bf[4];
      #pragma unroll
      for (int i = 0; i < 4; i++) {
        int Ra = wm + i * 16 + lane15;
        af[i] = *(const half8*)(As + Ra * 64 + ((ks * 4 + quad) ^ (Ra & 7)) * 8);
      }
      #pragma unroll
      for (int i = 0; i < 4; i++) {
        int Rb = wn + i * 16 + lane15;
        bf[i] = *(const half8*)(Bs + Rb * 64 + ((ks * 4 + quad) ^ (Rb & 7)) * 8);
      }
      #pragma unroll
      for (int mi = 0; mi < 4; mi++)
        #pragma unroll
        for (int ni = 0; ni < 4; ni++)
          acc[mi][ni] = __builtin_amdgcn_mfma_f32_16x16x32_f16(af[mi], bf[ni], acc[mi][ni], 0, 0, 0);
    }
  }
#undef QKV_STAGE
  // bias (b_attn) BEFORE rope, matching reference
  #pragma unroll
  for (int ni = 0; ni < 4; ni++) {
    float bv = bias[bn0 + wn + ni * 16 + lane15];
    #pragma unroll
    for (int mi = 0; mi < 4; mi++)
      #pragma unroll
      for (int r = 0; r < 4; r++) acc[mi][ni][r] += bv;
  }

  int third = bn0 >> 10;                   // 0=Q, 1=K, 2=V (block-uniform)
  if (third < 2) {
    half_t* Ob = (third == 0) ? Qo : Ko;
    int h = ((bn0 & 1023) + wn) >> 6;      // head for this wave's columns
    #pragma unroll
    for (int mi = 0; mi < 4; mi++) {
      int mrow = bm0 + wm + mi * 16 + quad * 4;
      int bq = mrow >> 11, tq = mrow & 2047;
      half_t* outp = Ob + ((size_t)(bq * 16 + h) * T_SEQ + tq) * HD;
      #pragma unroll
      for (int p = 0; p < 2; p++) {        // pair (d=j, d=j+32), j = p*16+lane15
        int j = p * 16 + lane15;
        #pragma unroll
        for (int r = 0; r < 4; r++) {
          float2 cs = tbl[(tq + r) * 32 + j];
          float a1 = acc[mi][p][r], a2 = acc[mi][p + 2][r];
          float o1 = a1 * cs.x - a2 * cs.y;
          float o2 = a1 * cs.y + a2 * cs.x;
          if (third == 0) { o1 *= QSCALE; o2 *= QSCALE; }
          outp[r * HD + j]      = (half_t)o1;
          outp[r * HD + j + 32] = (half_t)o2;
        }
      }
    }
  } else {
    // V: transpose through LDS, store blocked [bh][t/64][d][t%64]
    __syncthreads();                       // all waves done reading smem
    half_t* vt = &smem[0][0];              // [128][130], 33280B < 64KB
    #pragma unroll
    for (int mi = 0; mi < 4; mi++)
      #pragma unroll
      for (int ni = 0; ni < 4; ni++) {
        int tl = wm + mi * 16 + quad * 4, nl = wn + ni * 16 + lane15;
        #pragma unroll
        for (int r = 0; r < 4; r++)
          vt[(tl + r) * 130 + nl] = (half_t)acc[mi][ni][r];
      }
    __syncthreads();
    int hV = (bn0 - 2048) >> 6;
    int bq = bm0 >> 11, tq0 = bm0 & 2047;
    int c8 = (tid & 7) * 8;                // 8 lanes cover one 64-t row chunk
    #pragma unroll
    for (int p = 0; p < 8; p++) {
      int gr = p * 32 + (tid >> 3);        // 256 rows: (h2, d, tblk)
      int tb = gr & 1, d = (gr >> 1) & 63, h2 = gr >> 7;
      half8 vv;
      #pragma unroll
      for (int jj = 0; jj < 8; jj++)
        vv[jj] = vt[(tb * 64 + c8 + jj) * 130 + h2 * 64 + d];
      *(half8*)(Vo + ((size_t)((bq * 16 + hV + h2) * 32 + (tq0 >> 6) + tb) * 64 + d) * 64 + c8) = vv;
    }
  }
}

// ------------- causal flash v5: 2 kv-steps per barrier (128KB LDS) -------------
// R8 counters: FETCH 71->12MB (XCD swizzle worked; K/V L2-resident) yet dur
// unchanged -> NOT memory-bound. Bound by per-round serialization: each
// __syncthreads drains vmcnt(0) (including the just-issued prefetch) and
// converges 16 waves, ~16x per block. v5 stages 64KB (2 kv-steps x 2 parities)
// per barrier: barriers/block 16 -> 8, and each DMA batch gets a 2x-longer
// compute phase to land under. LDS 128KB (1 block/CU, as before; precedent:
// 8-phase template). (cvt_pkrtz micro-opt dropped after R9 compile fail —
// guide m240: compiler fuses scalar casts to v_cvt_pkrtz itself.)
template <bool DIAG>
__device__ __forceinline__ void tile_mfma(const half_t* __restrict__ Kt,
                                          const half_t* __restrict__ Vt,
                                          half8 bq0, half8 bq1,
                                          f32x4 (&ot)[4], float& l,
                                          int lane15, int quad, int qloc) {
  f32x4 sacc[4];
  #pragma unroll
  for (int s = 0; s < 4; s++) {
    int R_ = s * 16 + lane15;
    half8 ak0 = *(const half8*)(Kt + R_ * 64 + ((quad) ^ (R_ & 7)) * 8);
    half8 ak1 = *(const half8*)(Kt + R_ * 64 + ((4 + quad) ^ (R_ & 7)) * 8);
    f32x4 z = {};
    z = __builtin_amdgcn_mfma_f32_16x16x32_f16(ak0, bq0, z, 0, 0, 0);
    sacc[s] = __builtin_amdgcn_mfma_f32_16x16x32_f16(ak1, bq1, z, 0, 0, 0);
  }
  #pragma unroll
  for (int s = 0; s < 4; s++) {
    half4 bp;
    #pragma unroll
    for (int r = 0; r < 4; r++) {
      float sv = sacc[s][r];
      if (DIAG && (s * 16 + quad * 4 + r > qloc)) sv = -1.0e30f;
      float p = exp2f(fminf(sv, 14.0f));
      l += p;
      bp[r] = (half_t)p;
    }
    #pragma unroll
    for (int nm = 0; nm < 4; nm++) {
      int Rv = nm * 16 + lane15;
      half4 av = *(const half4*)(Vt + Rv * 64 +
                                 ((2 * s + (quad >> 1)) ^ (Rv & 7)) * 8 +
                                 (quad & 1) * 4);
      ot[nm] = __builtin_amdgcn_mfma_f32_16x16x16f16(av, bp, ot[nm], 0, 0, 0);
    }
  }
}

// Stage super-round s_: kv tiles {4s, 4s+1} (sub 0) and {4s+2, 4s+3} (sub 1)
// of K and V into buffer bb. 1024 threads x 4 load_lds16 (16B) = 64KB.
// Waves 0-7 serve even tiles (parity 0), waves 8-15 odd (parity 1).
// Max staged tile index = 4*7+3 = 31 -> always within the bh's K/V.
#define STAGE2(bb, s_)                                                         \
  {                                                                            \
    int gS = wave >> 3;                                                        \
    int idx = (wave & 7) * 64 + lane;                                          \
    int rr_ = idx >> 3, cc = (idx & 7) ^ (rr_ & 7);                            \
    _Pragma("unroll")                                                          \
    for (int sub = 0; sub < 2; sub++) {                                        \
      int j = 4 * (s_) + 2 * sub + gS;                                         \
      load_lds16(Kb + (size_t)(j * 64 + rr_) * HD + cc * 8,                    \
                 &KV[bb][sub][0][gS][0] + idx * 8);                            \
      load_lds16(Vb + (size_t)j * 4096 + rr_ * 64 + cc * 8,                    \
                 &KV[bb][sub][1][gS][0] + idx * 8);                            \
    }                                                                          \
  }

__global__ __launch_bounds__(1024, 4) void k_flash(const half_t* __restrict__ Qg,
                                                   const half_t* __restrict__ Kg,
                                                   const half_t* __restrict__ Vg,
                                                   half_t* __restrict__ y) {
  __shared__ half_t KV[2][2][2][2][4096];  // [buf][sub][K/V][parity][64*64] 128KB
  // XCD-colocation swizzle (XCD = flat % 8): all 8 blocks of one bh share an
  // XCD -> K/V L2-resident (verified R8: FETCH 71.5 -> 12.4MB).
  int flat = (int)blockIdx.x + 8 * (int)blockIdx.y;
  int x  = (flat >> 3) & 7;                // q-tile pair id 0..7
  int bh = (flat & 7) | ((flat >> 6) << 3);
  int b = bh >> 4, h = bh & 15;
  int tid = threadIdx.x;
  int wave = tid >> 6, lane = tid & 63;
  int g = wave >> 3, wq = wave & 7;        // kv-parity group, q-warp in group
  int lane15 = lane & 15, quad = lane >> 4;
  const half_t* Qb = Qg + (size_t)bh * T_SEQ * HD;
  const half_t* Kb = Kg + (size_t)bh * T_SEQ * HD;
  const half_t* Vb = Vg + (size_t)bh * HD * T_SEQ;

  int qtA = x, qtB = 15 - x;               // A < B always
  int jA = 2 * qtA, jB = 2 * qtB;          // diagonal kv-tile bases
  int qlA = qtA * 128 + wq * 16 + lane15;
  int qlB = qtB * 128 + wq * 16 + lane15;
  half8 aq0 = *(const half8*)(Qb + (size_t)qlA * HD + quad * 8);
  half8 aq1 = *(const half8*)(Qb + (size_t)qlA * HD + 32 + quad * 8);
  half8 bq0 = *(const half8*)(Qb + (size_t)qlB * HD + quad * 8);
  half8 bq1 = *(const half8*)(Qb + (size_t)qlB * HD + 32 + quad * 8);
  f32x4 otA[4] = {}, otB[4] = {};
  float lA = 0.f, lB = 0.f;

  int R = 16 - x;                          // old rounds; tiles consumed 2/round
  int S = (R + 1) >> 1;                    // super-rounds (4 tiles per stage)
  STAGE2(0, 0);
  for (int s = 0; s < S; s++) {
    __syncthreads();                       // stage(s) DMA drained & visible
    if (s + 1 < S) STAGE2((s + 1) & 1, s + 1);  // prefetch overlaps compute
    #pragma unroll
    for (int sub = 0; sub < 2; sub++) {
      const half_t* Kt = &KV[s & 1][sub][0][g][0];
      const half_t* Vt = &KV[s & 1][sub][1][g][0];
      int j = 2 * (2 * s + sub) + g;       // this group's kv tile
      // tile A (q rows 128x..128x+127): active while j <= jA+1
      if (j < jA)
        tile_mfma<false>(Kt, Vt, aq0, aq1, otA, lA, lane15, quad, 0);
      else if (j == jA)                    // parity 0 -> group 0 only
        tile_mfma<true>(Kt, Vt, aq0, aq1, otA, lA, lane15, quad,
                        wq * 16 + lane15);
      else if (j == jA + 1 && wq >= 4)     // parity 1 -> group 1; wq<4 masked
        tile_mfma<true>(Kt, Vt, aq0, aq1, otA, lA, lane15, quad,
                        (wq - 4) * 16 + lane15);
      // tile B (q rows 128(15-x)..): active while j <= jB+1
      if (j < jB)
        tile_mfma<false>(Kt, Vt, bq0, bq1, otB, lB, lane15, quad, 0);
      else if (j == jB)
        tile_mfma<true>(Kt, Vt, bq0, bq1, otB, lB, lane15, quad,
                        wq * 16 + lane15);
      else if (j == jB + 1 && wq >= 4)
        tile_mfma<true>(Kt, Vt, bq0, bq1, otB, lB, lane15, quad,
                        (wq - 4) * 16 + lane15);
    }
  }
  // per-wave l: sum the 4 quads holding each q-column
  lA += __shfl_xor(lA, 16); lA += __shfl_xor(lA, 32);
  lB += __shfl_xor(lB, 16); lB += __shfl_xor(lB, 32);
  // cross-group combine via LDS (reuse KV region, 512*17*4B = 34.8KB <= 128KB)
  float* cb = (float*)&KV[0][0][0][0][0];
  int ci = (wq * 64 + lane) * 17;          // stride 17 floats: conflict-free
  // ---- tile A ----
  __syncthreads();                         // all K/V reads done; region free
  if (g == 1) {
    #pragma unroll
    for (int nm = 0; nm < 4; nm++)
      #pragma unroll
      for (int r = 0; r < 4; r++) cb[ci + nm * 4 + r] = otA[nm][r];
    cb[ci + 16] = lA;
  }
  __syncthreads();
  if (g == 0) {
    #pragma unroll
    for (int nm = 0; nm < 4; nm++)
      #pragma unroll
      for (int r = 0; r < 4; r++) otA[nm][r] += cb[ci + nm * 4 + r];
    lA += cb[ci + 16];
    float invl = 1.0f / lA;
    int t = qtA * 128 + wq * 16 + lane15;
    half_t* yr = y + (size_t)(b * T_SEQ + t) * C_DIM + h * 64;
    #pragma unroll
    for (int nm = 0; nm < 4; nm++) {
      half4 o4;
      #pragma unroll
      for (int r = 0; r < 4; r++) o4[r] = (half_t)(otA[nm][r] * invl);
      *(half4*)(yr + nm * 16 + quad * 4) = o4;   // 8B store
    }
  }
  // ---- tile B ----
  __syncthreads();
  if (g == 1) {
    #pragma unroll
    for (int nm = 0; nm < 4; nm++)
      #pragma unroll
      for (int r = 0; r < 4; r++) cb[ci + nm * 4 + r] = otB[nm][r];
    cb[ci + 16] = lB;
  }
  __syncthreads();
  if (g == 0) {
    #pragma unroll
    for (int nm = 0; nm < 4; nm++)
      #pragma unroll
      for (int r = 0; r < 4; r++) otB[nm][r] += cb[ci + nm * 4 + r];
    lB += cb[ci + 16];
    float invl = 1.0f / lB;
    int t = qtB * 128 + wq * 16 + lane15;
    half_t* yr = y + (size_t)(b * T_SEQ + t) * C_DIM + h * 64;
    #pragma unroll
    for (int nm = 0; nm < 4; nm++) {
      half4 o4;
      #pragma unroll
      for (int r = 0; r < 4; r++) o4[r] = (half_t)(otB[nm][r] * invl);
      *(half4*)(yr + nm * 16 + quad * 4) = o4;   // 8B store
    }
  }
  #undef STAGE2
}

extern "C" void kernel_launch(void* const* d_in, const int* in_sizes, int n_in,
                              void* d_out, int out_size, void* d_ws, size_t ws_size,
                              hipStream_t stream) {
  const float* x      = (const float*)d_in[0];
  const float* w_attn = (const float*)d_in[1];
  const float* b_attn = (const float*)d_in[2];
  const float* w_proj = (const float*)d_in[3];
  const float* b_proj = (const float*)d_in[4];
  float* out = (float*)d_out;

  char* ws = (char*)d_ws;
  const size_t MB = 1u << 20;
  half_t* xb  = (half_t*)(ws);             // 8 MB  x in f16
  half_t* wT  = (half_t*)(ws + 8 * MB);    // 6 MB  w_attn^T f16 [3072][1024]
  half_t* wpT = (half_t*)(ws + 14 * MB);   // 2 MB  w_proj^T f16 [1024][1024]
  half_t* Q   = (half_t*)(ws + 16 * MB);   // 8 MB  [bh][t][d]  (pre-scaled)
  half_t* Kb  = (half_t*)(ws + 24 * MB);   // 8 MB  [bh][t][d]
  half_t* Vt  = (half_t*)(ws + 32 * MB);   // 8 MB  [bh][t/64][d][t%64] blocked
  half_t* y   = (half_t*)(ws + 40 * MB);   // 8 MB  attn out f16
  float2* tbl = (float2*)(ws + 48 * MB);   // 512KB rope table [2048][32]

  k_prep<<<4096 + 768 + 256 + 256, 256, 0, stream>>>(x, xb, w_attn, wT,
                                                     w_proj, wpT, tbl);
  k_gemm_qkv<<<dim3(N_QKV / 128, M_ROWS / 128), 256, 0, stream>>>(
      xb, wT, b_attn, tbl, Q, Kb, Vt);
  k_flash<<<dim3(8, B_SZ * N_HEADS), 1024, 0, stream>>>(Q, Kb, Vt, y);
  k_gemm<float, 64><<<dim3(C_DIM / 64, M_ROWS / 128), 256, 0, stream>>>(
      y, wpT, b_proj, out, M_ROWS, C_DIM, C_DIM);
}

// Round 11
// 171.499 us; speedup vs baseline: 1.1079x; 1.0335x over previous
//
#include <hip/hip_runtime.h>
#include <hip/hip_bf16.h>
#include <cmath>

typedef _Float16 half_t;
typedef half_t half4 __attribute__((ext_vector_type(4)));
typedef half_t half8 __attribute__((ext_vector_type(8)));
typedef float f32x4 __attribute__((ext_vector_type(4)));

#define N_HEADS 16
#define HD      64
#define T_SEQ   2048
#define B_SZ    2
#define C_DIM   1024
#define M_ROWS  (B_SZ * T_SEQ)   /* 4096 */
#define N_QKV   (3 * C_DIM)      /* 3072 */
#define QSCALE  0.18033688f      /* 0.125 * log2(e), folded into Q at rope */

__device__ inline void load_lds16(const half_t* g, half_t* l) {
  __builtin_amdgcn_global_load_lds(
      (const __attribute__((address_space(1))) void*)g,
      (__attribute__((address_space(3))) void*)l, 16, 0, 0);
}

// ---- fused prep: x->f16 (0..4095), w_attn^T (..4863), w_proj^T (..5119),
// ---- rope cos/sin table (5120..5375): tbl[t][j] = {cos,sin}(t*10000^(-j/32))
__global__ __launch_bounds__(256) void k_prep(const float* __restrict__ x,
                                              half_t* __restrict__ xb,
                                              const float* __restrict__ wa,
                                              half_t* __restrict__ wT,
                                              const float* __restrict__ wp,
                                              half_t* __restrict__ wpT,
                                              float2* __restrict__ tbl) {
  __shared__ float tile[64][65];
  int bid = blockIdx.x, tid = threadIdx.x;
  if (bid < 4096) {
    int i = (bid * 256 + tid) * 4;
    float4 v = *(const float4*)(x + i);
    half_t o[4] = {(half_t)v.x, (half_t)v.y, (half_t)v.z, (half_t)v.w};
    *(ulong1*)(xb + i) = *(ulong1*)o;
    return;
  }
  if (bid >= 5120) {                       // rope table: 65536 entries
    int idx = (bid - 5120) * 256 + tid;
    int t = idx >> 5, j = idx & 31;
    float inv = exp2f(-(float)j * (13.287712379549449f / 32.0f));
    float s, c;
    sincosf((float)t * inv, &s, &c);
    tbl[idx] = make_float2(c, s);
    return;
  }
  const float* in; half_t* out; int K, N, id;
  if (bid < 4864) { id = bid - 4096; in = wa; out = wT;  K = 1024; N = 3072; }
  else            { id = bid - 4864; in = wp; out = wpT; K = 1024; N = 1024; }
  int n0 = (id % (N / 64)) * 64, k0 = (id / (N / 64)) * 64;
  int tx = tid & 63, ty = tid >> 6;
  #pragma unroll
  for (int i = 0; i < 64; i += 4)
    tile[ty + i][tx] = in[(size_t)(k0 + ty + i) * N + n0 + tx];
  __syncthreads();
  #pragma unroll
  for (int i = 0; i < 64; i += 4) {
    int r = ty + i;
    out[(size_t)(n0 + r) * K + k0 + tx] = (half_t)tile[tx][r];
  }
}

// ------------- GEMM: C = A(f16,[M][K]) * Bt(f16,[N][K])^T + bias, OT out ----
// 128xTN tile, BK=64, double-buffered prefetch (one barrier per K-iter).
template <typename OT, int TN>
__global__ __launch_bounds__(256) void k_gemm(const half_t* __restrict__ A,
                                              const half_t* __restrict__ Bt,
                                              const float* __restrict__ bias,
                                              OT* __restrict__ C,
                                              int M, int N, int K) {
  constexpr int NI = TN / 32;          // n-fragments per wave
  __shared__ half_t As[2][128 * 64];
  __shared__ half_t Bs[2][TN * 64];
  int tid = threadIdx.x;
  int wave = tid >> 6, lane = tid & 63;
  int lane15 = lane & 15, quad = lane >> 4;
  int wm = (wave >> 1) * 64, wn = (wave & 1) * (TN / 2);
  int bm0 = blockIdx.y * 128, bn0 = blockIdx.x * TN;
  f32x4 acc[4][NI] = {};

#define G_STAGE(bb, kb)                                                        \
  {                                                                            \
    const half_t* Ag = A + (size_t)bm0 * K + (kb);                             \
    const half_t* Bg = Bt + (size_t)bn0 * K + (kb);                            \
    _Pragma("unroll")                                                          \
    for (int p = 0; p < 4; p++) {                                              \
      int fc = wave * 4 * 64 + p * 64 + lane;                                  \
      int r = fc >> 3, c = (fc & 7) ^ (r & 7);                                 \
      load_lds16(Ag + (size_t)r * K + c * 8, &As[bb][0] + (wave * 4 + p) * 512); \
    }                                                                          \
    _Pragma("unroll")                                                          \
    for (int p = 0; p < NI; p++) {                                             \
      int fc = wave * NI * 64 + p * 64 + lane;                                 \
      int r = fc >> 3, c = (fc & 7) ^ (r & 7);                                 \
      load_lds16(Bg + (size_t)r * K + c * 8, &Bs[bb][0] + (wave * NI + p) * 512); \
    }                                                                          \
  }

  G_STAGE(0, 0);
  int NT = K / 64;
  for (int kt = 0; kt < NT; kt++) {
    __syncthreads();                       // buf[kt&1] DMA drained & visible
    if (kt + 1 < NT) G_STAGE((kt + 1) & 1, (kt + 1) * 64);
    const half_t* Asb = &As[kt & 1][0];
    const half_t* Bsb = &Bs[kt & 1][0];
    #pragma unroll
    for (int ks = 0; ks < 2; ks++) {
      half8 af[4], bf[NI];
      #pragma unroll
      for (int i = 0; i < 4; i++) {
        int Ra = wm + i * 16 + lane15;
        af[i] = *(const half8*)(Asb + Ra * 64 + ((ks * 4 + quad) ^ (Ra & 7)) * 8);
      }
      #pragma unroll
      for (int i = 0; i < NI; i++) {
        int Rb = wn + i * 16 + lane15;
        bf[i] = *(const half8*)(Bsb + Rb * 64 + ((ks * 4 + quad) ^ (Rb & 7)) * 8);
      }
      #pragma unroll
      for (int mi = 0; mi < 4; mi++)
        #pragma unroll
        for (int ni = 0; ni < NI; ni++)
          acc[mi][ni] = __builtin_amdgcn_mfma_f32_16x16x32_f16(af[mi], bf[ni], acc[mi][ni], 0, 0, 0);
    }
  }
#undef G_STAGE
  #pragma unroll
  for (int mi = 0; mi < 4; mi++)
    #pragma unroll
    for (int ni = 0; ni < NI; ni++) {
      int n = bn0 + wn + ni * 16 + lane15;
      float bv = bias[n];
      int mrow = bm0 + wm + mi * 16 + quad * 4;
      #pragma unroll
      for (int r = 0; r < 4; r++)
        C[(size_t)(mrow + r) * N + n] = (OT)(acc[mi][ni][r] + bv);
    }
}

// ------------- fused QKV GEMM + bias + RoPE + reorg (v3: 512 threads) -------------
// R11: occupancy pinned at ~14% in EVERY run (R4/R5/R10) — per-thread regs
// (64 AGPR acc + ~96 VGPR ~ 160 combined) cap residency at ~2 waves/SIMD.
// v3 keeps the 128x128 tile + BK=64 + dbuf but spreads it over 512 threads
// (8 waves, 4M x 2N; wave tile 32x64): acc 64->32 AGPR, frags 64->24 VGPR,
// __launch_bounds__(512,4) pins 4 waves/SIMD -> 2 blocks/CU = 16 waves/CU.
// Each wave's 64-wide N span = exactly one head (rope epilogue simplifies).
__global__ __launch_bounds__(512, 4) void k_gemm_qkv(const half_t* __restrict__ A,
                                                     const half_t* __restrict__ Bt,
                                                     const float* __restrict__ bias,
                                                     const float2* __restrict__ tbl,
                                                     half_t* __restrict__ Qo,
                                                     half_t* __restrict__ Ko,
                                                     half_t* __restrict__ Vo) {
  __shared__ half_t smem[2][16384];        // per buf: As 8192h | Bs 8192h (64KB)
  int tid = threadIdx.x;
  int wave = tid >> 6, lane = tid & 63;
  int lane15 = lane & 15, quad = lane >> 4;
  int wm = (wave >> 1) * 32, wn = (wave & 1) * 64;   // 4M x 2N wave grid
  int bm0 = blockIdx.y * 128, bn0 = blockIdx.x * 128;
  f32x4 acc[2][4] = {};                    // [mi][ni]: 32 AGPR

#define QKV_STAGE(bb, kb)                                                      \
  {                                                                            \
    const half_t* Ag = A + (size_t)bm0 * C_DIM + (kb);                         \
    const half_t* Bg = Bt + (size_t)bn0 * C_DIM + (kb);                        \
    _Pragma("unroll")                                                          \
    for (int p = 0; p < 2; p++) {                                              \
      int fc = (wave * 2 + p) * 64 + lane;                                     \
      int r = fc >> 3, c = (fc & 7) ^ (r & 7);                                 \
      load_lds16(Ag + (size_t)r * C_DIM + c * 8,                               \
                 &smem[bb][0] + (wave * 2 + p) * 512);                         \
      load_lds16(Bg + (size_t)r * C_DIM + c * 8,                               \
                 &smem[bb][8192] + (wave * 2 + p) * 512);                      \
    }                                                                          \
  }

  QKV_STAGE(0, 0);
  for (int kt = 0; kt < 16; kt++) {
    __syncthreads();                       // buf[kt&1] DMA drained & visible
    if (kt < 15) QKV_STAGE((kt + 1) & 1, (kt + 1) * 64);
    const half_t* As = &smem[kt & 1][0];
    const half_t* Bs = &smem[kt & 1][8192];
    #pragma unroll
    for (int ks = 0; ks < 2; ks++) {
      half8 af[2], bf[4];
      #pragma unroll
      for (int i = 0; i < 2; i++) {
        int Ra = wm + i * 16 + lane15;
        af[i] = *(const half8*)(As + Ra * 64 + ((ks * 4 + quad) ^ (Ra & 7)) * 8);
      }
      #pragma unroll
      for (int i = 0; i < 4; i++) {
        int Rb = wn + i * 16 + lane15;
        bf[i] = *(const half8*)(Bs + Rb * 64 + ((ks * 4 + quad) ^ (Rb & 7)) * 8);
      }
      #pragma unroll
      for (int mi = 0; mi < 2; mi++)
        #pragma unroll
        for (int ni = 0; ni < 4; ni++)
          acc[mi][ni] = __builtin_amdgcn_mfma_f32_16x16x32_f16(af[mi], bf[ni], acc[mi][ni], 0, 0, 0);
    }
  }
#undef QKV_STAGE
  // bias (b_attn) BEFORE rope, matching reference
  #pragma unroll
  for (int ni = 0; ni < 4; ni++) {
    float bv = bias[bn0 + wn + ni * 16 + lane15];
    #pragma unroll
    for (int mi = 0; mi < 2; mi++)
      #pragma unroll
      for (int r = 0; r < 4; r++) acc[mi][ni][r] += bv;
  }

  int third = bn0 >> 10;                   // 0=Q, 1=K, 2=V (block-uniform)
  if (third < 2) {
    half_t* Ob = (third == 0) ? Qo : Ko;
    int h = ((bn0 & 1023) + wn) >> 6;      // one head per wave (wn in {0,64})
    #pragma unroll
    for (int mi = 0; mi < 2; mi++) {
      int mrow = bm0 + wm + mi * 16 + quad * 4;
      int bq = mrow >> 11, tq = mrow & 2047;
      half_t* outp = Ob + ((size_t)(bq * 16 + h) * T_SEQ + tq) * HD;
      #pragma unroll
      for (int p = 0; p < 2; p++) {        // pair (d=j, d=j+32), j = p*16+lane15
        int j = p * 16 + lane15;
        #pragma unroll
        for (int r = 0; r < 4; r++) {
          float2 cs = tbl[(tq + r) * 32 + j];
          float a1 = acc[mi][p][r], a2 = acc[mi][p + 2][r];
          float o1 = a1 * cs.x - a2 * cs.y;
          float o2 = a1 * cs.y + a2 * cs.x;
          if (third == 0) { o1 *= QSCALE; o2 *= QSCALE; }
          outp[r * HD + j]      = (half_t)o1;
          outp[r * HD + j + 32] = (half_t)o2;
        }
      }
    }
  } else {
    // V: transpose through LDS, store blocked [bh][t/64][d][t%64]
    __syncthreads();                       // all waves done reading smem
    half_t* vt = &smem[0][0];              // [128][130], 33280B < 64KB
    #pragma unroll
    for (int mi = 0; mi < 2; mi++)
      #pragma unroll
      for (int ni = 0; ni < 4; ni++) {
        int tl = wm + mi * 16 + quad * 4, nl = wn + ni * 16 + lane15;
        #pragma unroll
        for (int r = 0; r < 4; r++)
          vt[(tl + r) * 130 + nl] = (half_t)acc[mi][ni][r];
      }
    __syncthreads();
    int hV = (bn0 - 2048) >> 6;
    int bq = bm0 >> 11, tq0 = bm0 & 2047;
    int c8 = (tid & 7) * 8;                // 8 lanes cover one 64-t row chunk
    #pragma unroll
    for (int p = 0; p < 4; p++) {
      int gr = p * 64 + (tid >> 3);        // 256 rows: (h2, d, tblk)
      int tb = gr & 1, d = (gr >> 1) & 63, h2 = gr >> 7;
      half8 vv;
      #pragma unroll
      for (int jj = 0; jj < 8; jj++)
        vv[jj] = vt[(tb * 64 + c8 + jj) * 130 + h2 * 64 + d];
      *(half8*)(Vo + ((size_t)((bq * 16 + hV + h2) * 32 + (tq0 >> 6) + tb) * 64 + d) * 64 + c8) = vv;
    }
  }
}

// ------------- causal flash v5: 2 kv-steps per barrier (128KB LDS) -------------
// R10: worked (flash dropped out of top-5, <52.6us). Unchanged this round.
template <bool DIAG>
__device__ __forceinline__ void tile_mfma(const half_t* __restrict__ Kt,
                                          const half_t* __restrict__ Vt,
                                          half8 bq0, half8 bq1,
                                          f32x4 (&ot)[4], float& l,
                                          int lane15, int quad, int qloc) {
  f32x4 sacc[4];
  #pragma unroll
  for (int s = 0; s < 4; s++) {
    int R_ = s * 16 + lane15;
    half8 ak0 = *(const half8*)(Kt + R_ * 64 + ((quad) ^ (R_ & 7)) * 8);
    half8 ak1 = *(const half8*)(Kt + R_ * 64 + ((4 + quad) ^ (R_ & 7)) * 8);
    f32x4 z = {};
    z = __builtin_amdgcn_mfma_f32_16x16x32_f16(ak0, bq0, z, 0, 0, 0);
    sacc[s] = __builtin_amdgcn_mfma_f32_16x16x32_f16(ak1, bq1, z, 0, 0, 0);
  }
  #pragma unroll
  for (int s = 0; s < 4; s++) {
    half4 bp;
    #pragma unroll
    for (int r = 0; r < 4; r++) {
      float sv = sacc[s][r];
      if (DIAG && (s * 16 + quad * 4 + r > qloc)) sv = -1.0e30f;
      float p = exp2f(fminf(sv, 14.0f));
      l += p;
      bp[r] = (half_t)p;
    }
    #pragma unroll
    for (int nm = 0; nm < 4; nm++) {
      int Rv = nm * 16 + lane15;
      half4 av = *(const half4*)(Vt + Rv * 64 +
                                 ((2 * s + (quad >> 1)) ^ (Rv & 7)) * 8 +
                                 (quad & 1) * 4);
      ot[nm] = __builtin_amdgcn_mfma_f32_16x16x16f16(av, bp, ot[nm], 0, 0, 0);
    }
  }
}

// Stage super-round s_: kv tiles {4s, 4s+1} (sub 0) and {4s+2, 4s+3} (sub 1)
// of K and V into buffer bb. 1024 threads x 4 load_lds16 (16B) = 64KB.
#define STAGE2(bb, s_)                                                         \
  {                                                                            \
    int gS = wave >> 3;                                                        \
    int idx = (wave & 7) * 64 + lane;                                          \
    int rr_ = idx >> 3, cc = (idx & 7) ^ (rr_ & 7);                            \
    _Pragma("unroll")                                                          \
    for (int sub = 0; sub < 2; sub++) {                                        \
      int j = 4 * (s_) + 2 * sub + gS;                                         \
      load_lds16(Kb + (size_t)(j * 64 + rr_) * HD + cc * 8,                    \
                 &KV[bb][sub][0][gS][0] + idx * 8);                            \
      load_lds16(Vb + (size_t)j * 4096 + rr_ * 64 + cc * 8,                    \
                 &KV[bb][sub][1][gS][0] + idx * 8);                            \
    }                                                                          \
  }

__global__ __launch_bounds__(1024, 4) void k_flash(const half_t* __restrict__ Qg,
                                                   const half_t* __restrict__ Kg,
                                                   const half_t* __restrict__ Vg,
                                                   half_t* __restrict__ y) {
  __shared__ half_t KV[2][2][2][2][4096];  // [buf][sub][K/V][parity][64*64] 128KB
  // XCD-colocation swizzle (XCD = flat % 8): all 8 blocks of one bh share an
  // XCD -> K/V L2-resident (verified R8: FETCH 71.5 -> 12.4MB).
  int flat = (int)blockIdx.x + 8 * (int)blockIdx.y;
  int x  = (flat >> 3) & 7;                // q-tile pair id 0..7
  int bh = (flat & 7) | ((flat >> 6) << 3);
  int b = bh >> 4, h = bh & 15;
  int tid = threadIdx.x;
  int wave = tid >> 6, lane = tid & 63;
  int g = wave >> 3, wq = wave & 7;        // kv-parity group, q-warp in group
  int lane15 = lane & 15, quad = lane >> 4;
  const half_t* Qb = Qg + (size_t)bh * T_SEQ * HD;
  const half_t* Kb = Kg + (size_t)bh * T_SEQ * HD;
  const half_t* Vb = Vg + (size_t)bh * HD * T_SEQ;

  int qtA = x, qtB = 15 - x;               // A < B always
  int jA = 2 * qtA, jB = 2 * qtB;          // diagonal kv-tile bases
  int qlA = qtA * 128 + wq * 16 + lane15;
  int qlB = qtB * 128 + wq * 16 + lane15;
  half8 aq0 = *(const half8*)(Qb + (size_t)qlA * HD + quad * 8);
  half8 aq1 = *(const half8*)(Qb + (size_t)qlA * HD + 32 + quad * 8);
  half8 bq0 = *(const half8*)(Qb + (size_t)qlB * HD + quad * 8);
  half8 bq1 = *(const half8*)(Qb + (size_t)qlB * HD + 32 + quad * 8);
  f32x4 otA[4] = {}, otB[4] = {};
  float lA = 0.f, lB = 0.f;

  int R = 16 - x;                          // old rounds; tiles consumed 2/round
  int S = (R + 1) >> 1;                    // super-rounds (4 tiles per stage)
  STAGE2(0, 0);
  for (int s = 0; s < S; s++) {
    __syncthreads();                       // stage(s) DMA drained & visible
    if (s + 1 < S) STAGE2((s + 1) & 1, s + 1);  // prefetch overlaps compute
    #pragma unroll
    for (int sub = 0; sub < 2; sub++) {
      const half_t* Kt = &KV[s & 1][sub][0][g][0];
      const half_t* Vt = &KV[s & 1][sub][1][g][0];
      int j = 2 * (2 * s + sub) + g;       // this group's kv tile
      // tile A (q rows 128x..128x+127): active while j <= jA+1
      if (j < jA)
        tile_mfma<false>(Kt, Vt, aq0, aq1, otA, lA, lane15, quad, 0);
      else if (j == jA)                    // parity 0 -> group 0 only
        tile_mfma<true>(Kt, Vt, aq0, aq1, otA, lA, lane15, quad,
                        wq * 16 + lane15);
      else if (j == jA + 1 && wq >= 4)     // parity 1 -> group 1; wq<4 masked
        tile_mfma<true>(Kt, Vt, aq0, aq1, otA, lA, lane15, quad,
                        (wq - 4) * 16 + lane15);
      // tile B (q rows 128(15-x)..): active while j <= jB+1
      if (j < jB)
        tile_mfma<false>(Kt, Vt, bq0, bq1, otB, lB, lane15, quad, 0);
      else if (j == jB)
        tile_mfma<true>(Kt, Vt, bq0, bq1, otB, lB, lane15, quad,
                        wq * 16 + lane15);
      else if (j == jB + 1 && wq >= 4)
        tile_mfma<true>(Kt, Vt, bq0, bq1, otB, lB, lane15, quad,
                        (wq - 4) * 16 + lane15);
    }
  }
  // per-wave l: sum the 4 quads holding each q-column
  lA += __shfl_xor(lA, 16); lA += __shfl_xor(lA, 32);
  lB += __shfl_xor(lB, 16); lB += __shfl_xor(lB, 32);
  // cross-group combine via LDS (reuse KV region, 512*17*4B = 34.8KB <= 128KB)
  float* cb = (float*)&KV[0][0][0][0][0];
  int ci = (wq * 64 + lane) * 17;          // stride 17 floats: conflict-free
  // ---- tile A ----
  __syncthreads();                         // all K/V reads done; region free
  if (g == 1) {
    #pragma unroll
    for (int nm = 0; nm < 4; nm++)
      #pragma unroll
      for (int r = 0; r < 4; r++) cb[ci + nm * 4 + r] = otA[nm][r];
    cb[ci + 16] = lA;
  }
  __syncthreads();
  if (g == 0) {
    #pragma unroll
    for (int nm = 0; nm < 4; nm++)
      #pragma unroll
      for (int r = 0; r < 4; r++) otA[nm][r] += cb[ci + nm * 4 + r];
    lA += cb[ci + 16];
    float invl = 1.0f / lA;
    int t = qtA * 128 + wq * 16 + lane15;
    half_t* yr = y + (size_t)(b * T_SEQ + t) * C_DIM + h * 64;
    #pragma unroll
    for (int nm = 0; nm < 4; nm++) {
      half4 o4;
      #pragma unroll
      for (int r = 0; r < 4; r++) o4[r] = (half_t)(otA[nm][r] * invl);
      *(half4*)(yr + nm * 16 + quad * 4) = o4;   // 8B store
    }
  }
  // ---- tile B ----
  __syncthreads();
  if (g == 1) {
    #pragma unroll
    for (int nm = 0; nm < 4; nm++)
      #pragma unroll
      for (int r = 0; r < 4; r++) cb[ci + nm * 4 + r] = otB[nm][r];
    cb[ci + 16] = lB;
  }
  __syncthreads();
  if (g == 0) {
    #pragma unroll
    for (int nm = 0; nm < 4; nm++)
      #pragma unroll
      for (int r = 0; r < 4; r++) otB[nm][r] += cb[ci + nm * 4 + r];
    lB += cb[ci + 16];
    float invl = 1.0f / lB;
    int t = qtB * 128 + wq * 16 + lane15;
    half_t* yr = y + (size_t)(b * T_SEQ + t) * C_DIM + h * 64;
    #pragma unroll
    for (int nm = 0; nm < 4; nm++) {
      half4 o4;
      #pragma unroll
      for (int r = 0; r < 4; r++) o4[r] = (half_t)(otB[nm][r] * invl);
      *(half4*)(yr + nm * 16 + quad * 4) = o4;   // 8B store
    }
  }
  #undef STAGE2
}

extern "C" void kernel_launch(void* const* d_in, const int* in_sizes, int n_in,
                              void* d_out, int out_size, void* d_ws, size_t ws_size,
                              hipStream_t stream) {
  const float* x      = (const float*)d_in[0];
  const float* w_attn = (const float*)d_in[1];
  const float* b_attn = (const float*)d_in[2];
  const float* w_proj = (const float*)d_in[3];
  const float* b_proj = (const float*)d_in[4];
  float* out = (float*)d_out;

  char* ws = (char*)d_ws;
  const size_t MB = 1u << 20;
  half_t* xb  = (half_t*)(ws);             // 8 MB  x in f16
  half_t* wT  = (half_t*)(ws + 8 * MB);    // 6 MB  w_attn^T f16 [3072][1024]
  half_t* wpT = (half_t*)(ws + 14 * MB);   // 2 MB  w_proj^T f16 [1024][1024]
  half_t* Q   = (half_t*)(ws + 16 * MB);   // 8 MB  [bh][t][d]  (pre-scaled)
  half_t* Kb  = (half_t*)(ws + 24 * MB);   // 8 MB  [bh][t][d]
  half_t* Vt  = (half_t*)(ws + 32 * MB);   // 8 MB  [bh][t/64][d][t%64] blocked
  half_t* y   = (half_t*)(ws + 40 * MB);   // 8 MB  attn out f16
  float2* tbl = (float2*)(ws + 48 * MB);   // 512KB rope table [2048][32]

  k_prep<<<4096 + 768 + 256 + 256, 256, 0, stream>>>(x, xb, w_attn, wT,
                                                     w_proj, wpT, tbl);
  k_gemm_qkv<<<dim3(N_QKV / 128, M_ROWS / 128), 512, 0, stream>>>(
      xb, wT, b_attn, tbl, Q, Kb, Vt);
  k_flash<<<dim3(8, B_SZ * N_HEADS), 1024, 0, stream>>>(Q, Kb, Vt, y);
  k_gemm<float, 64><<<dim3(C_DIM / 64, M_ROWS / 128), 256, 0, stream>>>(
      y, wpT, b_proj, out, M_ROWS, C_DIM, C_DIM);
}